// Round 7
// baseline (668.700 us; speedup 1.0000x reference)
//
#include <hip/hip_runtime.h>
#include <hip/hip_bf16.h>
#include <cstdint>

#define DEV __device__ __forceinline__
typedef __attribute__((ext_vector_type(8))) short short8;
typedef __attribute__((ext_vector_type(4))) float f32x4;
typedef unsigned short u16;

DEV float b2f(u16 u) { union { unsigned int i; float f; } x; x.i = (unsigned)u << 16; return x.f; }
DEV u16 f2b(float f) { __hip_bfloat16 h = __float2bfloat16(f); return *(u16*)&h; }
DEV float rdin(const void* p, size_t i, int isbf) {
  return isbf ? __bfloat162float(((const __hip_bfloat16*)p)[i]) : ((const float*)p)[i];
}
DEV void wrout(void* p, size_t i, float v, int isbf) {
  if (isbf) ((__hip_bfloat16*)p)[i] = __float2bfloat16(v);
  else      ((float*)p)[i] = v;
}
DEV short8 ld8(const void* p, size_t idx, int isbf) {
  if (isbf) return *(const short8*)((const u16*)p + idx);
  const float* f = (const float*)p + idx;
  float4 x = *(const float4*)f, y = *(const float4*)(f + 4);
  short8 r;
  r[0] = f2b(x.x); r[1] = f2b(x.y); r[2] = f2b(x.z); r[3] = f2b(x.w);
  r[4] = f2b(y.x); r[5] = f2b(y.y); r[6] = f2b(y.z); r[7] = f2b(y.w);
  return r;
}
DEV void gl16(const u16* g, u16* l) {
  __builtin_amdgcn_global_load_lds(
      (const __attribute__((address_space(1))) void*)g,
      (__attribute__((address_space(3))) void*)l, 16, 0, 0);
}
DEV void bar() {
  asm volatile("" ::: "memory");
  __builtin_amdgcn_s_barrier();
  asm volatile("" ::: "memory");
}

__global__ __launch_bounds__(256) void detect_k(const u16* w, int* flag) {
  __shared__ int cnt[256];
  int tid = threadIdx.x, c = 0;
  for (int i = tid; i < 4096; i += 256) {
    u16 v = w[i];
    int e = (v >> 7) & 0xFF;
    if (v == 0 || (e >= 0x60 && e <= 0x9F)) c++;
  }
  cnt[tid] = c;
  __syncthreads();
  for (int s = 128; s > 0; s >>= 1) { if (tid < s) cnt[tid] += cnt[tid + s]; __syncthreads(); }
  if (tid == 0) *flag = (cnt[0] > 3600) ? 1 : 0;
}

__global__ __launch_bounds__(256) void patchify_k(const void* F0, const void* F1,
                                                  u16* dst, const int* dflag) {
  int isbf = *dflag;
  int bid = blockIdx.x;
  int z = bid >> 8, rem = bid & 255, b = rem >> 5, y = rem & 31;
  const void* F = z ? F1 : F0;
  int x = threadIdx.x & 31, pj = threadIdx.x >> 5;
  u16* drow = dst + (size_t)(z * 8192 + b * 1024 + y * 32 + x) * 768;
#pragma unroll
  for (int i = 0; i < 6; i++) {
    int pair = i * 8 + pj;
    int c = pair >> 4, ky = pair & 15;
    size_t src = ((size_t)((b * 3 + c) * 512 + y * 16 + ky)) * 512 + x * 16;
    short8 v0 = ld8(F, src, isbf);
    short8 v1 = ld8(F, src + 8, isbf);
    u16* dp = drow + c * 256 + ky * 16;
    *(short8*)dp = v0;
    *(short8*)(dp + 8) = v1;
  }
}

__global__ __launch_bounds__(256) void wconv_k(const void* wm, const void* wq,
                                               u16* dst, const int* dflag) {
  int isbf = *dflag;
  int gi = blockIdx.x * 256 + threadIdx.x;
  size_t e0 = (size_t)gi * 8;
  const void* src = e0 < 393216 ? wm : wq;
  size_t off = e0 < 393216 ? e0 : e0 - 393216;
  *(short8*)&dst[e0] = ld8(src, off, isbf);
}

__global__ __launch_bounds__(256) void kvconv_k(const void* valW, const void* keyW,
                                                u16* dst, const int* dflag) {
  int isbf = *dflag;
  int idx = blockIdx.x * 256 + threadIdx.x;
  size_t e0 = (size_t)idx * 8;
  int row = (int)(e0 >> 9);
  const void* src = row < 256 ? valW : keyW;
  size_t off = row < 256 ? e0 : e0 - (size_t)256 * 512;
  *(short8*)&dst[e0] = ld8(src, off, isbf);
}

struct PA {
  const void* W0; const void* W1; size_t bs; int K; int rowsplit; int zsel; int ws16; int rowmax1;
  DEV short8 l8(int row, int k, int b, int zz, int isbf) const {
    const void* W = W0; int r = row;
    if (zsel && zz == 2) W = W1;
    else if (rowsplit && row >= rowsplit) { W = W1; r = row - rowsplit; if (r > rowmax1) r = rowmax1; }
    return ld8(W, (size_t)b * bs + (size_t)r * K + k, ws16 ? 1 : isbf);
  }
  DEV const u16* ga(int row, int k, int b, int zz) const {
    int r = row; if (rowsplit && r > rowmax1) r = rowmax1;
    return (const u16*)W0 + (size_t)b * bs + (size_t)r * K + k;
  }
};
struct PBws {
  const u16* X; int rs; size_t zs;
  DEV short8 l8(int t, int k, int zz, int) const {
    return *(const short8*)(X + (size_t)zz * zs + (size_t)t * rs + k);
  }
  DEV const u16* ga(int t, int k, int zz) const {
    return X + (size_t)zz * zs + (size_t)t * rs + k;
  }
};
struct PBc3 {
  const u16* X; int C; int shift;
  DEV short8 l8(int t, int k, int, int) const {
    int tap = k >> shift, c0 = k & (C - 1);
    int dy = tap / 3, dx = tap - dy * 3;
    int pos = t & 1023, y = pos >> 5, x = pos & 31;
    int iy = y + dy - 1, ix = x + dx - 1;
    if ((unsigned)iy >= 32u || (unsigned)ix >= 32u) { short8 z = {0,0,0,0,0,0,0,0}; return z; }
    return *(const short8*)(X + (size_t)(((t >> 10) * 1024) + iy * 32 + ix) * C + c0);
  }
};

struct Epi {
  int mode;
  u16 *o16, *o16b, *o16c;
  size_t zs; int ts, moff, mmax;
  const void *bias, *bias2; int bzsel;
  const void *maskA, *maskB;
  const float* rscale;
  float scale; int relu, doexp;
  DEV void store1(int m, int t, int z, float v, int isbf) const {
    if (m >= mmax) return;
    int b = t >> 10, pos = t & 1023;
    if (m < 256) {
      v += rdin(bias, m, isbf);
      if (z < 2) {
        const void* mk = z ? maskB : maskA;
        v *= rdin(mk, ((size_t)(b * 512 + (pos >> 5) * 16) << 9) + (pos & 31) * 16, isbf);
        o16[((size_t)(b * 256 + m)) * 2048 + (size_t)z * 1024 + pos] = f2b(v);
      } else {
        o16b[(size_t)t * 512 + m] = f2b(v);
      }
    } else {
      v += rdin(bias2, m - 256, isbf);
      o16c[((size_t)z * 8192 + t) * 64 + (m - 256)] = f2b(v);
    }
  }
};

DEV void epilogue(const Epi& ep, f32x4 (&acc)[4][4], u16* sh, int isbf, int tid,
                  int col16, int quad, int wm, int wn, int zz, int m0, int n0, int nbase) {
  if (ep.mode == 1) {
#pragma unroll
    for (int mt = 0; mt < 4; mt++)
#pragma unroll
      for (int nt = 0; nt < 4; nt++)
#pragma unroll
        for (int r = 0; r < 4; r++) {
          int m = m0 + wm * 64 + mt * 16 + quad * 4 + r;
          int t = nbase + n0 + wn * 64 + nt * 16 + col16;
          ep.store1(m, t, zz, acc[mt][nt][r], isbf);
        }
    return;
  }
  if (ep.mode == 2) {
    float* pf = (float*)ep.o16;
#pragma unroll
    for (int mt = 0; mt < 4; mt++)
#pragma unroll
      for (int nt = 0; nt < 4; nt++)
#pragma unroll
        for (int r = 0; r < 4; r++) {
          int m = m0 + wm * 64 + mt * 16 + quad * 4 + r;
          int t = nbase + n0 + wn * 64 + nt * 16 + col16;
          pf[((size_t)(zz * 256 + m)) * 8192 + t] = acc[mt][nt][r];
        }
    return;
  }
  u16* T = sh;
  const int TS = 132;
  for (int p = 0; p < 2; p++) {
    __syncthreads();
    if (wn == p) {
#pragma unroll
      for (int mt = 0; mt < 4; mt++)
#pragma unroll
        for (int nt = 0; nt < 4; nt++) {
          int tl = nt * 16 + col16;
#pragma unroll
          for (int r2 = 0; r2 < 2; r2++) {
            int ml = wm * 64 + mt * 16 + quad * 4 + r2 * 2;
            float v0 = acc[mt][nt][r2 * 2] * ep.scale;
            float v1 = acc[mt][nt][r2 * 2 + 1] * ep.scale;
            if (ep.bias) {
              const void* bp = (ep.bzsel && zz == 2) ? ep.bias2 : ep.bias;
              v0 += rdin(bp, m0 + ml, isbf);
              v1 += rdin(bp, m0 + ml + 1, isbf);
            }
            if (ep.relu) { v0 = fmaxf(v0, 0.f); v1 = fmaxf(v1, 0.f); }
            unsigned int pk = (unsigned)f2b(v0) | ((unsigned)f2b(v1) << 16);
            *(unsigned int*)&T[tl * TS + ml] = pk;
          }
        }
    }
    __syncthreads();
    {
      int tl = tid >> 2, seg = tid & 3;
      int tg = nbase + n0 + p * 64 + tl;
      u16* op = ep.o16 + (size_t)zz * ep.zs + (size_t)tg * ep.ts + ep.moff + m0;
#pragma unroll
      for (int i = 0; i < 4; i++) {
        int c8 = seg + i * 4;
        short8 v = *(short8*)&T[tl * TS + c8 * 8];
        *(short8*)&op[c8 * 8] = v;
      }
    }
  }
}

// ---- GL GEMM: 128x128 tile, BK=64, 4 waves; SINGLE 32KB LDS buffer (m97-style):
// cross-block wave overlap does the latency hiding; 4 blocks/CU at VGPR<=128.
template <class PB>
__global__ __launch_bounds__(256, 4) void mgl(PA pa, PB pb, Epi ep, int ktiles, int nbase,
                                              const int* dflag) {
  __shared__ u16 sh[16384];
  int isbf = *dflag;
  int tid = threadIdx.x, lane = tid & 63;
  int col16 = lane & 15, quad = lane >> 4;
  int wv = tid >> 6, wm = wv >> 1, wn = wv & 1;
  int zz = blockIdx.z;
  int n0 = blockIdx.x * 128, m0 = blockIdx.y * 128;
  int bA = (nbase + n0) >> 10;

  f32x4 acc[4][4];
#pragma unroll
  for (int mt = 0; mt < 4; mt++)
#pragma unroll
    for (int nt = 0; nt < 4; nt++)
#pragma unroll
      for (int r = 0; r < 4; r++) acc[mt][nt][r] = 0.f;

  int rA[4], lA[4];
#pragma unroll
  for (int g = 0; g < 4; g++) {
    rA[g] = g * 32 + (tid >> 3);
    lA[g] = (tid & 7) ^ (rA[g] & 7);
  }

  for (int kt = 0; kt < ktiles; kt++) {
    int kk = kt * 64;
#pragma unroll
    for (int g = 0; g < 4; g++) {
      gl16(pa.ga(m0 + rA[g], kk + lA[g] * 8, bA, zz), sh + (size_t)(g * 256 + tid) * 8);
      gl16(pb.ga(nbase + n0 + rA[g], kk + lA[g] * 8, zz), sh + 8192 + (size_t)(g * 256 + tid) * 8);
    }
    asm volatile("s_waitcnt vmcnt(0)" ::: "memory");
    bar();
#pragma unroll
    for (int s = 0; s < 2; s++) {
      short8 af[4], bf[4];
      int cs = ((s * 4 + quad) ^ (col16 & 7)) << 3;
#pragma unroll
      for (int mt = 0; mt < 4; mt++)
        af[mt] = *(const short8*)&sh[(wm * 64 + mt * 16 + col16) * 64 + cs];
#pragma unroll
      for (int nt = 0; nt < 4; nt++)
        bf[nt] = *(const short8*)&sh[8192 + (wn * 64 + nt * 16 + col16) * 64 + cs];
#pragma unroll
      for (int mt = 0; mt < 4; mt++)
#pragma unroll
        for (int nt = 0; nt < 4; nt++)
          acc[mt][nt] = __builtin_amdgcn_mfma_f32_16x16x32_bf16(af[mt], bf[nt], acc[mt][nt], 0, 0, 0);
    }
    bar();   // all waves done reading before next issue overwrites
  }

  epilogue(ep, acc, sh, isbf, tid, col16, quad, wm, wn, zz, m0, n0, nbase);
}

// ---- reg-staged GEMM (PBc3 boundary zero-fill): single 32KB LDS + register prefetch ----
template <class PB>
__global__ __launch_bounds__(256, 4) void mg(PA pa, PB pb, Epi ep, int ktiles, int nbase,
                                             int ksplit, const int* dflag) {
  __shared__ u16 sh[16384];
  int isbf = *dflag;
  int tid = threadIdx.x, lane = tid & 63;
  int col16 = lane & 15, quad = lane >> 4;
  int wv = tid >> 6, wm = wv >> 1, wn = wv & 1;
  int zz = blockIdx.z;
  int kb = ksplit * zz;
  int n0 = blockIdx.x * 128, m0 = blockIdx.y * 128;
  int bA = (nbase + n0) >> 10;

  f32x4 acc[4][4];
#pragma unroll
  for (int mt = 0; mt < 4; mt++)
#pragma unroll
    for (int nt = 0; nt < 4; nt++)
#pragma unroll
      for (int r = 0; r < 4; r++) acc[mt][nt][r] = 0.f;

  int rA[4], lA[4];
#pragma unroll
  for (int g = 0; g < 4; g++) {
    rA[g] = g * 32 + (tid >> 3);
    lA[g] = (tid & 7) ^ (rA[g] & 7);
  }

  short8 ra[4], rb[4];
#pragma unroll
  for (int g = 0; g < 4; g++) {
    ra[g] = pa.l8(m0 + rA[g], kb + lA[g] * 8, bA, zz, isbf);
    rb[g] = pb.l8(nbase + n0 + rA[g], kb + lA[g] * 8, zz, isbf);
  }

  for (int kt = 0; kt < ktiles; kt++) {
    if (kt) __syncthreads();
#pragma unroll
    for (int g = 0; g < 4; g++) {
      *(short8*)&sh[(size_t)(g * 256 + tid) * 8] = ra[g];
      *(short8*)&sh[8192 + (size_t)(g * 256 + tid) * 8] = rb[g];
    }
    __syncthreads();
    if (kt + 1 < ktiles) {
      int kn = kb + (kt + 1) * 64;
#pragma unroll
      for (int g = 0; g < 4; g++) {
        ra[g] = pa.l8(m0 + rA[g], kn + lA[g] * 8, bA, zz, isbf);
        rb[g] = pb.l8(nbase + n0 + rA[g], kn + lA[g] * 8, zz, isbf);
      }
    }
#pragma unroll
    for (int s = 0; s < 2; s++) {
      short8 af[4], bf[4];
      int cs = ((s * 4 + quad) ^ (col16 & 7)) << 3;
#pragma unroll
      for (int mt = 0; mt < 4; mt++)
        af[mt] = *(const short8*)&sh[(wm * 64 + mt * 16 + col16) * 64 + cs];
#pragma unroll
      for (int nt = 0; nt < 4; nt++)
        bf[nt] = *(const short8*)&sh[8192 + (wn * 64 + nt * 16 + col16) * 64 + cs];
#pragma unroll
      for (int mt = 0; mt < 4; mt++)
#pragma unroll
        for (int nt = 0; nt < 4; nt++)
          acc[mt][nt] = __builtin_amdgcn_mfma_f32_16x16x32_bf16(af[mt], bf[nt], acc[mt][nt], 0, 0, 0);
    }
  }

  epilogue(ep, acc, sh, isbf, tid, col16, quad, wm, wn, zz, m0, n0, nbase);
}

// ---- fused split-KV flash attention; wave-parallel QK; XCD-aware block remap ----
__global__ __launch_bounds__(256) void attn_k(const u16* qk, const u16* memk,
                                              const u16* memv, float* pf, float* rsum) {
  __shared__ u16 sh[28672];            // Qt[64][64] | Kt[64][64] | Vt[256][64] | P[64][64]
  __shared__ float rsl[4][64];
  const int Qt = 0, Kt = 4096, Vt = 8192, Pl = 24576;
  int tid = threadIdx.x, lane = tid & 63;
  int col16 = lane & 15, quad = lane >> 4;
  int wv = tid >> 6;
  int xl = blockIdx.x;
  int x = ((xl & 7) << 4) | (xl >> 3);
  int b = x >> 4, qt = x & 15;
  int q0 = b * 1024 + qt * 64;
  int s = blockIdx.y;
  int kv0 = s * 512;

  rsl[wv][lane] = 0.f;

  int r32 = tid >> 3;
#pragma unroll
  for (int g = 0; g < 2; g++) {
    int row = g * 32 + r32;
    int k8 = (tid & 7) ^ (row & 7);
    gl16(qk + (size_t)(q0 + row) * 64 + k8 * 8, sh + Qt + (size_t)(g * 256 + tid) * 8);
  }
  {
#pragma unroll
    for (int g = 0; g < 2; g++) {
      int row = g * 32 + r32;
      int k8 = (tid & 7) ^ (row & 7);
      gl16(memk + ((size_t)(b * 2048 + kv0 + row)) * 64 + k8 * 8,
           sh + Kt + (size_t)(g * 256 + tid) * 8);
    }
#pragma unroll
    for (int g = 0; g < 8; g++) {
      int row = g * 32 + r32;
      int k8 = (tid & 7) ^ (row & 7);
      gl16(memv + ((size_t)(b * 256 + row)) * 2048 + kv0 + k8 * 8,
           sh + Vt + (size_t)(g * 256 + tid) * 8);
    }
  }
  __syncthreads();

  f32x4 acc_o[4][4];
#pragma unroll
  for (int mt = 0; mt < 4; mt++)
#pragma unroll
    for (int nt = 0; nt < 4; nt++)
#pragma unroll
      for (int r = 0; r < 4; r++) acc_o[mt][nt][r] = 0.f;

  for (int ch = 0; ch < 8; ch++) {
    {
      f32x4 acc_s[4];
#pragma unroll
      for (int nt = 0; nt < 4; nt++)
#pragma unroll
        for (int r = 0; r < 4; r++) acc_s[nt][r] = 0.f;
#pragma unroll
      for (int s2 = 0; s2 < 2; s2++) {
        int cs = ((s2 * 4 + quad) ^ (col16 & 7)) << 3;
        short8 af = *(const short8*)&sh[Kt + (wv * 16 + col16) * 64 + cs];
        short8 bf[4];
#pragma unroll
        for (int nt = 0; nt < 4; nt++)
          bf[nt] = *(const short8*)&sh[Qt + (nt * 16 + col16) * 64 + cs];
#pragma unroll
        for (int nt = 0; nt < 4; nt++)
          acc_s[nt] = __builtin_amdgcn_mfma_f32_16x16x32_bf16(af, bf[nt], acc_s[nt], 0, 0, 0);
      }
#pragma unroll
      for (int nt = 0; nt < 4; nt++) {
        int ql = nt * 16 + col16;
        float tsum = 0.f;
#pragma unroll
        for (int r = 0; r < 4; r++) {
          int kvl = wv * 16 + quad * 4 + r;
          u16 pb = f2b(__expf(0.125f * acc_s[nt][r]));
          tsum += b2f(pb);
          sh[Pl + ql * 64 + (((kvl >> 3) ^ (ql & 7)) << 3) + (kvl & 7)] = pb;
        }
        tsum += __shfl_xor(tsum, 16);
        tsum += __shfl_xor(tsum, 32);
        if (quad == 0) rsl[wv][ql] += tsum;
      }
    }
    __syncthreads();
    if (ch + 1 < 8) {
      int kvc = kv0 + (ch + 1) * 64;
#pragma unroll
      for (int g = 0; g < 2; g++) {
        int row = g * 32 + r32;
        int k8 = (tid & 7) ^ (row & 7);
        gl16(memk + ((size_t)(b * 2048 + kvc + row)) * 64 + k8 * 8,
             sh + Kt + (size_t)(g * 256 + tid) * 8);
      }
    }
#pragma unroll
    for (int s2 = 0; s2 < 2; s2++) {
      short8 af[4], bf[4];
      int cs = ((s2 * 4 + quad) ^ (col16 & 7)) << 3;
#pragma unroll
      for (int mt = 0; mt < 4; mt++)
        af[mt] = *(const short8*)&sh[Vt + (wv * 64 + mt * 16 + col16) * 64 + cs];
#pragma unroll
      for (int nt = 0; nt < 4; nt++)
        bf[nt] = *(const short8*)&sh[Pl + (nt * 16 + col16) * 64 + cs];
#pragma unroll
      for (int mt = 0; mt < 4; mt++)
#pragma unroll
        for (int nt = 0; nt < 4; nt++)
          acc_o[mt][nt] = __builtin_amdgcn_mfma_f32_16x16x32_bf16(af[mt], bf[nt], acc_o[mt][nt], 0, 0, 0);
    }
    __syncthreads();
    if (ch + 1 < 8) {
      int kvc = kv0 + (ch + 1) * 64;
#pragma unroll
      for (int g = 0; g < 8; g++) {
        int row = g * 32 + r32;
        int k8 = (tid & 7) ^ (row & 7);
        gl16(memv + ((size_t)(b * 256 + row)) * 2048 + kvc + k8 * 8,
             sh + Vt + (size_t)(g * 256 + tid) * 8);
      }
    }
    __syncthreads();
  }

#pragma unroll
  for (int mt = 0; mt < 4; mt++)
#pragma unroll
    for (int nt = 0; nt < 4; nt++)
#pragma unroll
      for (int r = 0; r < 4; r++) {
        int c = wv * 64 + mt * 16 + quad * 4 + r;
        int q = nt * 16 + col16;
        pf[((size_t)(s * 8192 + q0 + q)) * 256 + c] = acc_o[mt][nt][r];
      }
  if (tid < 64)
    atomicAdd(&rsum[q0 + tid], rsl[0][tid] + rsl[1][tid] + rsl[2][tid] + rsl[3][tid]);
}

__global__ __launch_bounds__(256) void acomb_k(const float* pf, const float* rsum,
                                               u16* fused) {
  int tid = threadIdx.x;
  int t = blockIdx.x * 2 + (tid >> 7);
  int cp = tid & 127;
  float inv = 1.f / rsum[t];
  float v0 = 0.f, v1 = 0.f;
#pragma unroll
  for (int s = 0; s < 4; s++) {
    const float* p = pf + ((size_t)(s * 8192 + t)) * 256 + cp * 2;
    v0 += p[0]; v1 += p[1];
  }
  unsigned int pk = (unsigned)f2b(v0 * inv) | ((unsigned)f2b(v1 * inv) << 16);
  *(unsigned int*)&fused[(size_t)t * 512 + 256 + cp * 2] = pk;
}

__global__ __launch_bounds__(256) void comb_k(const float* pf, const void* bias,
                                              u16* out, int ts, int moff, int npart,
                                              int relu, const int* dflag) {
  int isbf = *dflag;
  int tid = threadIdx.x;
  int t = blockIdx.x * 64 + (tid & 63);
  int m = blockIdx.y * 8 + ((tid >> 6) << 1);
  float v0 = 0.f, v1 = 0.f;
  for (int p = 0; p < npart; p++) {
    v0 += pf[(size_t)(p * 256 + m) * 8192 + t];
    v1 += pf[(size_t)(p * 256 + m + 1) * 8192 + t];
  }
  if (bias) { v0 += rdin(bias, m, isbf); v1 += rdin(bias, m + 1, isbf); }
  if (relu) { v0 = fmaxf(v0, 0.f); v1 = fmaxf(v1, 0.f); }
  unsigned int pk = (unsigned)f2b(v0) | ((unsigned)f2b(v1) << 16);
  *(unsigned int*)&out[(size_t)t * ts + moff + m] = pk;
}

__global__ __launch_bounds__(256) void wreorder_k(const void* src, u16* dst, int C,
                                                  int total, const int* dflag) {
  int idx = blockIdx.x * 256 + threadIdx.x;
  if (idx >= total) return;
  int isbf = *dflag;
  int nine_c = 9 * C;
  int m = idx / nine_c; int r = idx - m * nine_c;
  int tp = r / C; int c = r - tp * C;
  dst[idx] = f2b(rdin(src, (size_t)(m * C + c) * 9 + tp, isbf));
}

__global__ __launch_bounds__(256) void keyfix_k(const u16* kraw3, const void* mA,
                                                const void* mB, u16* memk, u16* qk,
                                                float* rsum, const int* dflag) {
  int isbf = *dflag;
  int z = blockIdx.y;
  int n = blockIdx.x * 256 + threadIdx.x;
  int b = n >> 10, pos = n & 1023;
  if (z == 0) rsum[n] = 0.f;
  float mv = 1.f;
  if (z == 0) mv = rdin(mA, ((size_t)(b * 512 + (pos >> 5) * 16) << 9) + (pos & 31) * 16, isbf);
  else if (z == 1) mv = rdin(mB, ((size_t)(b * 512 + (pos >> 5) * 16) << 9) + (pos & 31) * 16, isbf);
  const u16* src = kraw3 + ((size_t)z * 8192 + n) * 64;
  float v[64], ss = 0.f;
#pragma unroll
  for (int c = 0; c < 64; c++) { v[c] = b2f(src[c]) * mv; ss += v[c] * v[c]; }
  float inv = 1.f / fmaxf(sqrtf(ss), 1e-12f);
  u16* dst = (z < 2) ? memk + (size_t)(b * 2048 + z * 1024 + pos) * 64 : qk + (size_t)n * 64;
#pragma unroll
  for (int c = 0; c < 64; c++) dst[c] = f2b(v[c] * inv);
}

__global__ __launch_bounds__(256) void repcls_k(const u16* decf, const void* cwgt,
                                                const void* cbias, void* out_rep,
                                                float* logits, const int* dflag) {
  int isbf = *dflag;
  int tid = threadIdx.x, lane = tid & 63, wv = tid >> 6;
  int tok = blockIdx.x * 4 + wv;
  int b = tok >> 10, pos = tok & 1023;
  const u16* src = decf + (size_t)tok * 256;
  int c0 = lane * 4;
  float v[4], ss = 0.f, a0 = 0.f, a1 = 0.f;
#pragma unroll
  for (int j = 0; j < 4; j++) {
    float x = b2f(src[c0 + j]);
    v[j] = x; ss += x * x;
    a0 = fmaf(x, rdin(cwgt, c0 + j, isbf), a0);
    a1 = fmaf(x, rdin(cwgt, 256 + c0 + j, isbf), a1);
  }
#pragma unroll
  for (int off = 32; off > 0; off >>= 1) {
    ss += __shfl_down(ss, off); a0 += __shfl_down(a0, off); a1 += __shfl_down(a1, off);
  }
  ss = __shfl(ss, 0); a0 = __shfl(a0, 0); a1 = __shfl(a1, 0);
  float inv = 1.f / fmaxf(sqrtf(ss), 1e-12f);
#pragma unroll
  for (int j = 0; j < 4; j++)
    wrout(out_rep, ((size_t)(b * 256 + c0 + j) << 10) + pos, v[j] * inv, isbf);
  if (lane == 0) {
    logits[((size_t)(b * 2) << 10) + pos]     = a0 + rdin(cbias, 0, isbf);
    logits[((size_t)(b * 2 + 1) << 10) + pos] = a1 + rdin(cbias, 1, isbf);
  }
}

__global__ __launch_bounds__(256) void resize_k(const float* logits, void* out,
                                                size_t ebase, const int* dflag) {
  int isbf = *dflag;
  int idx = blockIdx.x * 256 + threadIdx.x;
  int ox = idx & 511, oy = (idx >> 9) & 511, c = (idx >> 18) & 1, b = idx >> 19;
  float fy = (oy + 0.5f) * 0.0625f - 0.5f;
  float fx = (ox + 0.5f) * 0.0625f - 0.5f;
  int y0 = (int)floorf(fy), x0 = (int)floorf(fx);
  float wy = fy - y0, wx = fx - x0;
  int y0c = max(y0, 0), y1c = min(y0 + 1, 31);
  int x0c = max(x0, 0), x1c = min(x0 + 1, 31);
  const float* L = logits + ((size_t)(b * 2 + c) << 10);
  float v00 = L[y0c * 32 + x0c], v01 = L[y0c * 32 + x1c];
  float v10 = L[y1c * 32 + x0c], v11 = L[y1c * 32 + x1c];
  float v = (1.f - wy) * ((1.f - wx) * v00 + wx * v01) + wy * ((1.f - wx) * v10 + wx * v11);
  wrout(out, ebase + (size_t)idx, v, isbf);
}

extern "C" void kernel_launch(void* const* d_in, const int* in_sizes, int n_in,
                              void* d_out, int out_size, void* d_ws, size_t ws_size,
                              hipStream_t stream) {
  const void* query  = d_in[0];  const void* prev   = d_in[1];
  const void* prevM  = d_in[2];  const void* first  = d_in[3];
  const void* firstM = d_in[4];  const void* encQw  = d_in[5];
  const void* encQb  = d_in[6];  const void* encMw  = d_in[7];
  const void* encMb  = d_in[8];  const void* keyW   = d_in[9];
  const void* keyB   = d_in[10]; const void* valW   = d_in[11];
  const void* valB   = d_in[12]; const void* dec1W  = d_in[13];
  const void* dec1B  = d_in[14]; const void* dec2W  = d_in[15];
  const void* dec2B  = d_in[16]; const void* clsW   = d_in[17];
  const void* clsB   = d_in[18];

  u16* W = (u16*)d_ws;
  int* dflag = (int*)W;                       // 16 u16
  float* rsum   = (float*)(W + 16);           // 8192 f32 (W+16..16400)
  float* logits = (float*)(W + 16400);        // 16384 f32 (..49168)
  u16* B0 = W + 49168;
  u16* Xp    = B0;                            // encode: [2][8192][768]
  u16* feat3 = B0 + 12582912;                 // [3][8192][512]
  u16* encWb = B0 + 25165824;                 // [2][512][768] bf16 (encode phase)
  u16* wr1   = B0;                            // [256][4608]
  u16* wr2   = B0 + 1179648;                  // [256][2304]
  u16* fused = B0 + 1769472;                  // [8192][512]
  u16* memv  = B0 + 5963776;                  // [8][256][2048]
  u16* memk  = B0 + 10158080;                 // [8][2048][64]
  u16* qk    = B0 + 11206656;                 // [8192][64]
  u16* kraw3 = B0 + 25165824;                 // [3][8192][64]; dead after keyfix
  u16* kvW   = B0 + 26738688;                 // [320][512] bf16; dead after keyval
  float* pf  = (float*)(B0 + 11730944);       // attn: [4][8192][256] f32; dec: [4][256][8192] f32
  u16* dbuf  = memv;
  u16* decf  = memv + 2097152;

  dim3 blk(256);
  detect_k<<<dim3(1), blk, 0, stream>>>((const u16*)encQw, dflag);

  wconv_k<<<dim3(384), blk, 0, stream>>>(encMw, encQw, encWb, dflag);
  patchify_k<<<dim3(512), blk, 0, stream>>>(first, prev, Xp, dflag);
  {
    PA a{encWb, 0, 0, 768, 0, 0, 1, 0};
    PBws b{Xp, 768, (size_t)8192 * 768};
    Epi e{0, feat3, 0, 0, (size_t)8192 * 512, 512, 0, 512,
          encMb, 0, 0, 0, 0, 0, 1.f, 1, 0};
    mgl<PBws><<<dim3(64, 4, 2), blk, 0, stream>>>(a, b, e, 12, 0, dflag);
  }
  patchify_k<<<dim3(256), blk, 0, stream>>>(query, query, Xp, dflag);
  {
    PA a{encWb + 393216, 0, 0, 768, 0, 0, 1, 0};
    PBws b{Xp, 768, 0};
    Epi e{0, feat3 + (size_t)2 * 8192 * 512, 0, 0, 0, 512, 0, 512,
          encQb, 0, 0, 0, 0, 0, 1.f, 1, 0};
    mgl<PBws><<<dim3(64, 4, 1), blk, 0, stream>>>(a, b, e, 12, 0, dflag);
  }

  wreorder_k<<<dim3(4608), blk, 0, stream>>>(dec1W, wr1, 512, 256 * 4608, dflag);
  wreorder_k<<<dim3(2304), blk, 0, stream>>>(dec2W, wr2, 256, 256 * 2304, dflag);
  kvconv_k<<<dim3(80), blk, 0, stream>>>(valW, keyW, kvW, dflag);

  {
    PA a{kvW, 0, 0, 512, 1, 0, 1, 319};
    PBws b{feat3, 512, (size_t)8192 * 512};
    Epi e{1, memv, fused, kraw3, 0, 0, 0, 320,
          valB, keyB, 0, firstM, prevM, 0, 1.f, 0, 0};
    mgl<PBws><<<dim3(64, 3, 3), blk, 0, stream>>>(a, b, e, 8, 0, dflag);
  }
  keyfix_k<<<dim3(32, 3), blk, 0, stream>>>(kraw3, firstM, prevM, memk, qk, rsum, dflag);

  attn_k<<<dim3(128, 4), blk, 0, stream>>>(qk, memk, memv, pf, rsum);
  acomb_k<<<dim3(4096), blk, 0, stream>>>(pf, rsum, fused);

  {
    PA a{wr1, 0, 0, 4608, 0, 0, 1, 0};
    PBc3 b{fused, 512, 9};
    Epi e{2, (u16*)pf, 0, 0, 0, 0, 0, 0,
          0, 0, 0, 0, 0, 0, 1.f, 0, 0};
    mg<PBc3><<<dim3(64, 2, 4), blk, 0, stream>>>(a, b, e, 18, 0, 1152, dflag);
    comb_k<<<dim3(128, 32), blk, 0, stream>>>(pf, dec1B, dbuf, 256, 0, 4, 1, dflag);
  }
  {
    PA a{wr2, 0, 0, 2304, 0, 0, 1, 0};
    PBc3 b{dbuf, 256, 8};
    Epi e{2, (u16*)pf, 0, 0, 0, 0, 0, 0,
          0, 0, 0, 0, 0, 0, 1.f, 0, 0};
    mg<PBc3><<<dim3(64, 2, 4), blk, 0, stream>>>(a, b, e, 9, 0, 576, dflag);
    comb_k<<<dim3(128, 32), blk, 0, stream>>>(pf, dec2B, decf, 256, 0, 4, 1, dflag);
  }

  repcls_k<<<dim3(2048), blk, 0, stream>>>(decf, clsW, clsB, d_out, logits, dflag);
  resize_k<<<dim3(16384), blk, 0, stream>>>(logits, d_out, (size_t)2097152, dflag);
}

// Round 8
// 466.630 us; speedup vs baseline: 1.4330x; 1.4330x over previous
//
#include <hip/hip_runtime.h>
#include <hip/hip_bf16.h>
#include <cstdint>

#define DEV __device__ __forceinline__
typedef __attribute__((ext_vector_type(8))) short short8;
typedef __attribute__((ext_vector_type(4))) float f32x4;
typedef unsigned short u16;

DEV float b2f(u16 u) { union { unsigned int i; float f; } x; x.i = (unsigned)u << 16; return x.f; }
DEV u16 f2b(float f) { __hip_bfloat16 h = __float2bfloat16(f); return *(u16*)&h; }
DEV float rdin(const void* p, size_t i, int isbf) {
  return isbf ? __bfloat162float(((const __hip_bfloat16*)p)[i]) : ((const float*)p)[i];
}
DEV void wrout(void* p, size_t i, float v, int isbf) {
  if (isbf) ((__hip_bfloat16*)p)[i] = __float2bfloat16(v);
  else      ((float*)p)[i] = v;
}
DEV short8 ld8(const void* p, size_t idx, int isbf) {
  if (isbf) return *(const short8*)((const u16*)p + idx);
  const float* f = (const float*)p + idx;
  float4 x = *(const float4*)f, y = *(const float4*)(f + 4);
  short8 r;
  r[0] = f2b(x.x); r[1] = f2b(x.y); r[2] = f2b(x.z); r[3] = f2b(x.w);
  r[4] = f2b(y.x); r[5] = f2b(y.y); r[6] = f2b(y.z); r[7] = f2b(y.w);
  return r;
}
DEV void gl16(const u16* g, u16* l) {
  __builtin_amdgcn_global_load_lds(
      (const __attribute__((address_space(1))) void*)g,
      (__attribute__((address_space(3))) void*)l, 16, 0, 0);
}
DEV void bar() {
  asm volatile("" ::: "memory");
  __builtin_amdgcn_s_barrier();
  asm volatile("" ::: "memory");
}

__global__ __launch_bounds__(256) void detect_k(const u16* w, int* flag) {
  __shared__ int cnt[256];
  int tid = threadIdx.x, c = 0;
  for (int i = tid; i < 4096; i += 256) {
    u16 v = w[i];
    int e = (v >> 7) & 0xFF;
    if (v == 0 || (e >= 0x60 && e <= 0x9F)) c++;
  }
  cnt[tid] = c;
  __syncthreads();
  for (int s = 128; s > 0; s >>= 1) { if (tid < s) cnt[tid] += cnt[tid + s]; __syncthreads(); }
  if (tid == 0) *flag = (cnt[0] > 3600) ? 1 : 0;
}

__global__ __launch_bounds__(256) void patchify_k(const void* F0, const void* F1,
                                                  u16* dst, const int* dflag) {
  int isbf = *dflag;
  int bid = blockIdx.x;
  int z = bid >> 8, rem = bid & 255, b = rem >> 5, y = rem & 31;
  const void* F = z ? F1 : F0;
  int x = threadIdx.x & 31, pj = threadIdx.x >> 5;
  u16* drow = dst + (size_t)(z * 8192 + b * 1024 + y * 32 + x) * 768;
#pragma unroll
  for (int i = 0; i < 6; i++) {
    int pair = i * 8 + pj;
    int c = pair >> 4, ky = pair & 15;
    size_t src = ((size_t)((b * 3 + c) * 512 + y * 16 + ky)) * 512 + x * 16;
    short8 v0 = ld8(F, src, isbf);
    short8 v1 = ld8(F, src + 8, isbf);
    u16* dp = drow + c * 256 + ky * 16;
    *(short8*)dp = v0;
    *(short8*)(dp + 8) = v1;
  }
}

__global__ __launch_bounds__(256) void wconv_k(const void* wm, const void* wq,
                                               u16* dst, const int* dflag) {
  int isbf = *dflag;
  int gi = blockIdx.x * 256 + threadIdx.x;
  size_t e0 = (size_t)gi * 8;
  const void* src = e0 < 393216 ? wm : wq;
  size_t off = e0 < 393216 ? e0 : e0 - 393216;
  *(short8*)&dst[e0] = ld8(src, off, isbf);
}

__global__ __launch_bounds__(256) void kvconv_k(const void* valW, const void* keyW,
                                                u16* dst, const int* dflag) {
  int isbf = *dflag;
  int idx = blockIdx.x * 256 + threadIdx.x;
  size_t e0 = (size_t)idx * 8;
  int row = (int)(e0 >> 9);
  const void* src = row < 256 ? valW : keyW;
  size_t off = row < 256 ? e0 : e0 - (size_t)256 * 512;
  *(short8*)&dst[e0] = ld8(src, off, isbf);
}

struct PA {
  const void* W0; const void* W1; size_t bs; int K; int rowsplit; int zsel; int ws16; int rowmax1;
  DEV short8 l8(int row, int k, int b, int zz, int isbf) const {
    const void* W = W0; int r = row;
    if (zsel && zz == 2) W = W1;
    else if (rowsplit && row >= rowsplit) { W = W1; r = row - rowsplit; if (r > rowmax1) r = rowmax1; }
    return ld8(W, (size_t)b * bs + (size_t)r * K + k, ws16 ? 1 : isbf);
  }
  DEV const u16* ga(int row, int k, int b, int zz) const {
    int r = row; if (rowsplit && r > rowmax1) r = rowmax1;
    return (const u16*)W0 + (size_t)b * bs + (size_t)r * K + k;
  }
};
struct PBws {
  const u16* X; int rs; size_t zs;
  DEV short8 l8(int t, int k, int zz, int) const {
    return *(const short8*)(X + (size_t)zz * zs + (size_t)t * rs + k);
  }
  DEV const u16* ga(int t, int k, int zz) const {
    return X + (size_t)zz * zs + (size_t)t * rs + k;
  }
};
struct PBc3 {
  const u16* X; int C; int shift;
  DEV short8 l8(int t, int k, int, int) const {
    int tap = k >> shift, c0 = k & (C - 1);
    int dy = tap / 3, dx = tap - dy * 3;
    int pos = t & 1023, y = pos >> 5, x = pos & 31;
    int iy = y + dy - 1, ix = x + dx - 1;
    if ((unsigned)iy >= 32u || (unsigned)ix >= 32u) { short8 z = {0,0,0,0,0,0,0,0}; return z; }
    return *(const short8*)(X + (size_t)(((t >> 10) * 1024) + iy * 32 + ix) * C + c0);
  }
};

struct Epi {
  int mode;
  u16 *o16, *o16b, *o16c;
  size_t zs; int ts, moff, mmax;
  const void *bias, *bias2; int bzsel;
  const void *maskA, *maskB;
  const float* rscale;
  float scale; int relu, doexp;
  DEV void store1(int m, int t, int z, float v, int isbf) const {
    if (m >= mmax) return;
    int b = t >> 10, pos = t & 1023;
    if (m < 256) {
      v += rdin(bias, m, isbf);
      if (z < 2) {
        const void* mk = z ? maskB : maskA;
        v *= rdin(mk, ((size_t)(b * 512 + (pos >> 5) * 16) << 9) + (pos & 31) * 16, isbf);
        o16[((size_t)(b * 256 + m)) * 2048 + (size_t)z * 1024 + pos] = f2b(v);
      } else {
        o16b[(size_t)t * 512 + m] = f2b(v);
      }
    } else {
      v += rdin(bias2, m - 256, isbf);
      o16c[((size_t)z * 8192 + t) * 64 + (m - 256)] = f2b(v);
    }
  }
};

DEV void epilogue(const Epi& ep, f32x4 (&acc)[4][4], u16* sh, int isbf, int tid,
                  int col16, int quad, int wm, int wn, int zz, int m0, int n0, int nbase) {
  if (ep.mode == 1) {
#pragma unroll
    for (int mt = 0; mt < 4; mt++)
#pragma unroll
      for (int nt = 0; nt < 4; nt++)
#pragma unroll
        for (int r = 0; r < 4; r++) {
          int m = m0 + wm * 64 + mt * 16 + quad * 4 + r;
          int t = nbase + n0 + wn * 64 + nt * 16 + col16;
          ep.store1(m, t, zz, acc[mt][nt][r], isbf);
        }
    return;
  }
  if (ep.mode == 2) {
    float* pf = (float*)ep.o16;
#pragma unroll
    for (int mt = 0; mt < 4; mt++)
#pragma unroll
      for (int nt = 0; nt < 4; nt++)
#pragma unroll
        for (int r = 0; r < 4; r++) {
          int m = m0 + wm * 64 + mt * 16 + quad * 4 + r;
          int t = nbase + n0 + wn * 64 + nt * 16 + col16;
          pf[((size_t)(zz * 256 + m)) * 8192 + t] = acc[mt][nt][r];
        }
    return;
  }
  u16* T = sh;
  const int TS = 132;
  for (int p = 0; p < 2; p++) {
    __syncthreads();
    if (wn == p) {
#pragma unroll
      for (int mt = 0; mt < 4; mt++)
#pragma unroll
        for (int nt = 0; nt < 4; nt++) {
          int tl = nt * 16 + col16;
#pragma unroll
          for (int r2 = 0; r2 < 2; r2++) {
            int ml = wm * 64 + mt * 16 + quad * 4 + r2 * 2;
            float v0 = acc[mt][nt][r2 * 2] * ep.scale;
            float v1 = acc[mt][nt][r2 * 2 + 1] * ep.scale;
            if (ep.bias) {
              const void* bp = (ep.bzsel && zz == 2) ? ep.bias2 : ep.bias;
              v0 += rdin(bp, m0 + ml, isbf);
              v1 += rdin(bp, m0 + ml + 1, isbf);
            }
            if (ep.relu) { v0 = fmaxf(v0, 0.f); v1 = fmaxf(v1, 0.f); }
            unsigned int pk = (unsigned)f2b(v0) | ((unsigned)f2b(v1) << 16);
            *(unsigned int*)&T[tl * TS + ml] = pk;
          }
        }
    }
    __syncthreads();
    {
      int tl = tid >> 2, seg = tid & 3;
      int tg = nbase + n0 + p * 64 + tl;
      u16* op = ep.o16 + (size_t)zz * ep.zs + (size_t)tg * ep.ts + ep.moff + m0;
#pragma unroll
      for (int i = 0; i < 4; i++) {
        int c8 = seg + i * 4;
        short8 v = *(short8*)&T[tl * TS + c8 * 8];
        *(short8*)&op[c8 * 8] = v;
      }
    }
  }
}

// ---- GL GEMM: 128x128 tile, BK=64, 4 waves; single 32KB LDS buffer; 4 blocks/CU ----
template <class PB>
__global__ __launch_bounds__(256, 4) void mgl(PA pa, PB pb, Epi ep, int ktiles, int nbase,
                                              const int* dflag) {
  __shared__ u16 sh[16384];
  int isbf = *dflag;
  int tid = threadIdx.x, lane = tid & 63;
  int col16 = lane & 15, quad = lane >> 4;
  int wv = tid >> 6, wm = wv >> 1, wn = wv & 1;
  int zz = blockIdx.z;
  int n0 = blockIdx.x * 128, m0 = blockIdx.y * 128;
  int bA = (nbase + n0) >> 10;

  f32x4 acc[4][4];
#pragma unroll
  for (int mt = 0; mt < 4; mt++)
#pragma unroll
    for (int nt = 0; nt < 4; nt++)
#pragma unroll
      for (int r = 0; r < 4; r++) acc[mt][nt][r] = 0.f;

  int rA[4], lA[4];
#pragma unroll
  for (int g = 0; g < 4; g++) {
    rA[g] = g * 32 + (tid >> 3);
    lA[g] = (tid & 7) ^ (rA[g] & 7);
  }

  for (int kt = 0; kt < ktiles; kt++) {
    int kk = kt * 64;
#pragma unroll
    for (int g = 0; g < 4; g++) {
      gl16(pa.ga(m0 + rA[g], kk + lA[g] * 8, bA, zz), sh + (size_t)(g * 256 + tid) * 8);
      gl16(pb.ga(nbase + n0 + rA[g], kk + lA[g] * 8, zz), sh + 8192 + (size_t)(g * 256 + tid) * 8);
    }
    asm volatile("s_waitcnt vmcnt(0)" ::: "memory");
    bar();
#pragma unroll
    for (int s = 0; s < 2; s++) {
      short8 af[4], bf[4];
      int cs = ((s * 4 + quad) ^ (col16 & 7)) << 3;
#pragma unroll
      for (int mt = 0; mt < 4; mt++)
        af[mt] = *(const short8*)&sh[(wm * 64 + mt * 16 + col16) * 64 + cs];
#pragma unroll
      for (int nt = 0; nt < 4; nt++)
        bf[nt] = *(const short8*)&sh[8192 + (wn * 64 + nt * 16 + col16) * 64 + cs];
#pragma unroll
      for (int mt = 0; mt < 4; mt++)
#pragma unroll
        for (int nt = 0; nt < 4; nt++)
          acc[mt][nt] = __builtin_amdgcn_mfma_f32_16x16x32_bf16(af[mt], bf[nt], acc[mt][nt], 0, 0, 0);
    }
    bar();   // all waves done reading before next issue overwrites
  }

  epilogue(ep, acc, sh, isbf, tid, col16, quad, wm, wn, zz, m0, n0, nbase);
}

// ---- reg-staged GEMM (PBc3): single 32KB LDS + register prefetch; NO min-wave bound
// (round-7 lesson: __launch_bounds__(256,4) forced VGPR=64 -> acc spill -> 400MB scratch)
template <class PB>
__global__ __launch_bounds__(256) void mg(PA pa, PB pb, Epi ep, int ktiles, int nbase,
                                          int ksplit, const int* dflag) {
  __shared__ u16 sh[16384];
  int isbf = *dflag;
  int tid = threadIdx.x, lane = tid & 63;
  int col16 = lane & 15, quad = lane >> 4;
  int wv = tid >> 6, wm = wv >> 1, wn = wv & 1;
  int zz = blockIdx.z;
  int kb = ksplit * zz;
  int n0 = blockIdx.x * 128, m0 = blockIdx.y * 128;
  int bA = (nbase + n0) >> 10;

  f32x4 acc[4][4];
#pragma unroll
  for (int mt = 0; mt < 4; mt++)
#pragma unroll
    for (int nt = 0; nt < 4; nt++)
#pragma unroll
      for (int r = 0; r < 4; r++) acc[mt][nt][r] = 0.f;

  int rA[4], lA[4];
#pragma unroll
  for (int g = 0; g < 4; g++) {
    rA[g] = g * 32 + (tid >> 3);
    lA[g] = (tid & 7) ^ (rA[g] & 7);
  }

  short8 ra[4], rb[4];
#pragma unroll
  for (int g = 0; g < 4; g++) {
    ra[g] = pa.l8(m0 + rA[g], kb + lA[g] * 8, bA, zz, isbf);
    rb[g] = pb.l8(nbase + n0 + rA[g], kb + lA[g] * 8, zz, isbf);
  }

  for (int kt = 0; kt < ktiles; kt++) {
    if (kt) __syncthreads();
#pragma unroll
    for (int g = 0; g < 4; g++) {
      *(short8*)&sh[(size_t)(g * 256 + tid) * 8] = ra[g];
      *(short8*)&sh[8192 + (size_t)(g * 256 + tid) * 8] = rb[g];
    }
    __syncthreads();
    if (kt + 1 < ktiles) {
      int kn = kb + (kt + 1) * 64;
#pragma unroll
      for (int g = 0; g < 4; g++) {
        ra[g] = pa.l8(m0 + rA[g], kn + lA[g] * 8, bA, zz, isbf);
        rb[g] = pb.l8(nbase + n0 + rA[g], kn + lA[g] * 8, zz, isbf);
      }
    }
#pragma unroll
    for (int s = 0; s < 2; s++) {
      short8 af[4], bf[4];
      int cs = ((s * 4 + quad) ^ (col16 & 7)) << 3;
#pragma unroll
      for (int mt = 0; mt < 4; mt++)
        af[mt] = *(const short8*)&sh[(wm * 64 + mt * 16 + col16) * 64 + cs];
#pragma unroll
      for (int nt = 0; nt < 4; nt++)
        bf[nt] = *(const short8*)&sh[8192 + (wn * 64 + nt * 16 + col16) * 64 + cs];
#pragma unroll
      for (int mt = 0; mt < 4; mt++)
#pragma unroll
        for (int nt = 0; nt < 4; nt++)
          acc[mt][nt] = __builtin_amdgcn_mfma_f32_16x16x32_bf16(af[mt], bf[nt], acc[mt][nt], 0, 0, 0);
    }
  }

  epilogue(ep, acc, sh, isbf, tid, col16, quad, wm, wn, zz, m0, n0, nbase);
}

// ---- fused split-KV flash attention; wave-parallel QK; XCD-aware block remap ----
__global__ __launch_bounds__(256) void attn_k(const u16* qk, const u16* memk,
                                              const u16* memv, float* pf, float* rsum) {
  __shared__ u16 sh[28672];            // Qt[64][64] | Kt[64][64] | Vt[256][64] | P[64][64]
  __shared__ float rsl[4][64];
  const int Qt = 0, Kt = 4096, Vt = 8192, Pl = 24576;
  int tid = threadIdx.x, lane = tid & 63;
  int col16 = lane & 15, quad = lane >> 4;
  int wv = tid >> 6;
  int xl = blockIdx.x;
  int x = ((xl & 7) << 4) | (xl >> 3);
  int b = x >> 4, qt = x & 15;
  int q0 = b * 1024 + qt * 64;
  int s = blockIdx.y;
  int kv0 = s * 512;

  rsl[wv][lane] = 0.f;

  int r32 = tid >> 3;
#pragma unroll
  for (int g = 0; g < 2; g++) {
    int row = g * 32 + r32;
    int k8 = (tid & 7) ^ (row & 7);
    gl16(qk + (size_t)(q0 + row) * 64 + k8 * 8, sh + Qt + (size_t)(g * 256 + tid) * 8);
  }
  {
#pragma unroll
    for (int g = 0; g < 2; g++) {
      int row = g * 32 + r32;
      int k8 = (tid & 7) ^ (row & 7);
      gl16(memk + ((size_t)(b * 2048 + kv0 + row)) * 64 + k8 * 8,
           sh + Kt + (size_t)(g * 256 + tid) * 8);
    }
#pragma unroll
    for (int g = 0; g < 8; g++) {
      int row = g * 32 + r32;
      int k8 = (tid & 7) ^ (row & 7);
      gl16(memv + ((size_t)(b * 256 + row)) * 2048 + kv0 + k8 * 8,
           sh + Vt + (size_t)(g * 256 + tid) * 8);
    }
  }
  __syncthreads();

  f32x4 acc_o[4][4];
#pragma unroll
  for (int mt = 0; mt < 4; mt++)
#pragma unroll
    for (int nt = 0; nt < 4; nt++)
#pragma unroll
      for (int r = 0; r < 4; r++) acc_o[mt][nt][r] = 0.f;

  for (int ch = 0; ch < 8; ch++) {
    {
      f32x4 acc_s[4];
#pragma unroll
      for (int nt = 0; nt < 4; nt++)
#pragma unroll
        for (int r = 0; r < 4; r++) acc_s[nt][r] = 0.f;
#pragma unroll
      for (int s2 = 0; s2 < 2; s2++) {
        int cs = ((s2 * 4 + quad) ^ (col16 & 7)) << 3;
        short8 af = *(const short8*)&sh[Kt + (wv * 16 + col16) * 64 + cs];
        short8 bf[4];
#pragma unroll
        for (int nt = 0; nt < 4; nt++)
          bf[nt] = *(const short8*)&sh[Qt + (nt * 16 + col16) * 64 + cs];
#pragma unroll
        for (int nt = 0; nt < 4; nt++)
          acc_s[nt] = __builtin_amdgcn_mfma_f32_16x16x32_bf16(af, bf[nt], acc_s[nt], 0, 0, 0);
      }
#pragma unroll
      for (int nt = 0; nt < 4; nt++) {
        int ql = nt * 16 + col16;
        float tsum = 0.f;
#pragma unroll
        for (int r = 0; r < 4; r++) {
          int kvl = wv * 16 + quad * 4 + r;
          u16 pb = f2b(__expf(0.125f * acc_s[nt][r]));
          tsum += b2f(pb);
          sh[Pl + ql * 64 + (((kvl >> 3) ^ (ql & 7)) << 3) + (kvl & 7)] = pb;
        }
        tsum += __shfl_xor(tsum, 16);
        tsum += __shfl_xor(tsum, 32);
        if (quad == 0) rsl[wv][ql] += tsum;
      }
    }
    __syncthreads();
    if (ch + 1 < 8) {
      int kvc = kv0 + (ch + 1) * 64;
#pragma unroll
      for (int g = 0; g < 2; g++) {
        int row = g * 32 + r32;
        int k8 = (tid & 7) ^ (row & 7);
        gl16(memk + ((size_t)(b * 2048 + kvc + row)) * 64 + k8 * 8,
             sh + Kt + (size_t)(g * 256 + tid) * 8);
      }
    }
#pragma unroll
    for (int s2 = 0; s2 < 2; s2++) {
      short8 af[4], bf[4];
      int cs = ((s2 * 4 + quad) ^ (col16 & 7)) << 3;
#pragma unroll
      for (int mt = 0; mt < 4; mt++)
        af[mt] = *(const short8*)&sh[Vt + (wv * 64 + mt * 16 + col16) * 64 + cs];
#pragma unroll
      for (int nt = 0; nt < 4; nt++)
        bf[nt] = *(const short8*)&sh[Pl + (nt * 16 + col16) * 64 + cs];
#pragma unroll
      for (int mt = 0; mt < 4; mt++)
#pragma unroll
        for (int nt = 0; nt < 4; nt++)
          acc_o[mt][nt] = __builtin_amdgcn_mfma_f32_16x16x32_bf16(af[mt], bf[nt], acc_o[mt][nt], 0, 0, 0);
    }
    __syncthreads();
    if (ch + 1 < 8) {
      int kvc = kv0 + (ch + 1) * 64;
#pragma unroll
      for (int g = 0; g < 8; g++) {
        int row = g * 32 + r32;
        int k8 = (tid & 7) ^ (row & 7);
        gl16(memv + ((size_t)(b * 256 + row)) * 2048 + kvc + k8 * 8,
             sh + Vt + (size_t)(g * 256 + tid) * 8);
      }
    }
    __syncthreads();
  }

#pragma unroll
  for (int mt = 0; mt < 4; mt++)
#pragma unroll
    for (int nt = 0; nt < 4; nt++)
#pragma unroll
      for (int r = 0; r < 4; r++) {
        int c = wv * 64 + mt * 16 + quad * 4 + r;
        int q = nt * 16 + col16;
        pf[((size_t)(s * 8192 + q0 + q)) * 256 + c] = acc_o[mt][nt][r];
      }
  if (tid < 64)
    atomicAdd(&rsum[q0 + tid], rsl[0][tid] + rsl[1][tid] + rsl[2][tid] + rsl[3][tid]);
}

__global__ __launch_bounds__(256) void acomb_k(const float* pf, const float* rsum,
                                               u16* fused) {
  int tid = threadIdx.x;
  int t = blockIdx.x * 2 + (tid >> 7);
  int cp = tid & 127;
  float inv = 1.f / rsum[t];
  float v0 = 0.f, v1 = 0.f;
#pragma unroll
  for (int s = 0; s < 4; s++) {
    const float* p = pf + ((size_t)(s * 8192 + t)) * 256 + cp * 2;
    v0 += p[0]; v1 += p[1];
  }
  unsigned int pk = (unsigned)f2b(v0 * inv) | ((unsigned)f2b(v1 * inv) << 16);
  *(unsigned int*)&fused[(size_t)t * 512 + 256 + cp * 2] = pk;
}

__global__ __launch_bounds__(256) void comb_k(const float* pf, const void* bias,
                                              u16* out, int ts, int moff, int npart,
                                              int relu, const int* dflag) {
  int isbf = *dflag;
  int tid = threadIdx.x;
  int t = blockIdx.x * 64 + (tid & 63);
  int m = blockIdx.y * 8 + ((tid >> 6) << 1);
  float v0 = 0.f, v1 = 0.f;
  for (int p = 0; p < npart; p++) {
    v0 += pf[(size_t)(p * 256 + m) * 8192 + t];
    v1 += pf[(size_t)(p * 256 + m + 1) * 8192 + t];
  }
  if (bias) { v0 += rdin(bias, m, isbf); v1 += rdin(bias, m + 1, isbf); }
  if (relu) { v0 = fmaxf(v0, 0.f); v1 = fmaxf(v1, 0.f); }
  unsigned int pk = (unsigned)f2b(v0) | ((unsigned)f2b(v1) << 16);
  *(unsigned int*)&out[(size_t)t * ts + moff + m] = pk;
}

__global__ __launch_bounds__(256) void wreorder_k(const void* src, u16* dst, int C,
                                                  int total, const int* dflag) {
  int idx = blockIdx.x * 256 + threadIdx.x;
  if (idx >= total) return;
  int isbf = *dflag;
  int nine_c = 9 * C;
  int m = idx / nine_c; int r = idx - m * nine_c;
  int tp = r / C; int c = r - tp * C;
  dst[idx] = f2b(rdin(src, (size_t)(m * C + c) * 9 + tp, isbf));
}

__global__ __launch_bounds__(256) void keyfix_k(const u16* kraw3, const void* mA,
                                                const void* mB, u16* memk, u16* qk,
                                                float* rsum, const int* dflag) {
  int isbf = *dflag;
  int z = blockIdx.y;
  int n = blockIdx.x * 256 + threadIdx.x;
  int b = n >> 10, pos = n & 1023;
  if (z == 0) rsum[n] = 0.f;
  float mv = 1.f;
  if (z == 0) mv = rdin(mA, ((size_t)(b * 512 + (pos >> 5) * 16) << 9) + (pos & 31) * 16, isbf);
  else if (z == 1) mv = rdin(mB, ((size_t)(b * 512 + (pos >> 5) * 16) << 9) + (pos & 31) * 16, isbf);
  const u16* src = kraw3 + ((size_t)z * 8192 + n) * 64;
  float v[64], ss = 0.f;
#pragma unroll
  for (int c = 0; c < 64; c++) { v[c] = b2f(src[c]) * mv; ss += v[c] * v[c]; }
  float inv = 1.f / fmaxf(sqrtf(ss), 1e-12f);
  u16* dst = (z < 2) ? memk + (size_t)(b * 2048 + z * 1024 + pos) * 64 : qk + (size_t)n * 64;
#pragma unroll
  for (int c = 0; c < 64; c++) dst[c] = f2b(v[c] * inv);
}

__global__ __launch_bounds__(256) void repcls_k(const u16* decf, const void* cwgt,
                                                const void* cbias, void* out_rep,
                                                float* logits, const int* dflag) {
  int isbf = *dflag;
  int tid = threadIdx.x, lane = tid & 63, wv = tid >> 6;
  int tok = blockIdx.x * 4 + wv;
  int b = tok >> 10, pos = tok & 1023;
  const u16* src = decf + (size_t)tok * 256;
  int c0 = lane * 4;
  float v[4], ss = 0.f, a0 = 0.f, a1 = 0.f;
#pragma unroll
  for (int j = 0; j < 4; j++) {
    float x = b2f(src[c0 + j]);
    v[j] = x; ss += x * x;
    a0 = fmaf(x, rdin(cwgt, c0 + j, isbf), a0);
    a1 = fmaf(x, rdin(cwgt, 256 + c0 + j, isbf), a1);
  }
#pragma unroll
  for (int off = 32; off > 0; off >>= 1) {
    ss += __shfl_down(ss, off); a0 += __shfl_down(a0, off); a1 += __shfl_down(a1, off);
  }
  ss = __shfl(ss, 0); a0 = __shfl(a0, 0); a1 = __shfl(a1, 0);
  float inv = 1.f / fmaxf(sqrtf(ss), 1e-12f);
#pragma unroll
  for (int j = 0; j < 4; j++)
    wrout(out_rep, ((size_t)(b * 256 + c0 + j) << 10) + pos, v[j] * inv, isbf);
  if (lane == 0) {
    logits[((size_t)(b * 2) << 10) + pos]     = a0 + rdin(cbias, 0, isbf);
    logits[((size_t)(b * 2 + 1) << 10) + pos] = a1 + rdin(cbias, 1, isbf);
  }
}

__global__ __launch_bounds__(256) void resize_k(const float* logits, void* out,
                                                size_t ebase, const int* dflag) {
  int isbf = *dflag;
  int idx = blockIdx.x * 256 + threadIdx.x;
  int ox = idx & 511, oy = (idx >> 9) & 511, c = (idx >> 18) & 1, b = idx >> 19;
  float fy = (oy + 0.5f) * 0.0625f - 0.5f;
  float fx = (ox + 0.5f) * 0.0625f - 0.5f;
  int y0 = (int)floorf(fy), x0 = (int)floorf(fx);
  float wy = fy - y0, wx = fx - x0;
  int y0c = max(y0, 0), y1c = min(y0 + 1, 31);
  int x0c = max(x0, 0), x1c = min(x0 + 1, 31);
  const float* L = logits + ((size_t)(b * 2 + c) << 10);
  float v00 = L[y0c * 32 + x0c], v01 = L[y0c * 32 + x1c];
  float v10 = L[y1c * 32 + x0c], v11 = L[y1c * 32 + x1c];
  float v = (1.f - wy) * ((1.f - wx) * v00 + wx * v01) + wy * ((1.f - wx) * v10 + wx * v11);
  wrout(out, ebase + (size_t)idx, v, isbf);
}

extern "C" void kernel_launch(void* const* d_in, const int* in_sizes, int n_in,
                              void* d_out, int out_size, void* d_ws, size_t ws_size,
                              hipStream_t stream) {
  const void* query  = d_in[0];  const void* prev   = d_in[1];
  const void* prevM  = d_in[2];  const void* first  = d_in[3];
  const void* firstM = d_in[4];  const void* encQw  = d_in[5];
  const void* encQb  = d_in[6];  const void* encMw  = d_in[7];
  const void* encMb  = d_in[8];  const void* keyW   = d_in[9];
  const void* keyB   = d_in[10]; const void* valW   = d_in[11];
  const void* valB   = d_in[12]; const void* dec1W  = d_in[13];
  const void* dec1B  = d_in[14]; const void* dec2W  = d_in[15];
  const void* dec2B  = d_in[16]; const void* clsW   = d_in[17];
  const void* clsB   = d_in[18];

  u16* W = (u16*)d_ws;
  int* dflag = (int*)W;                       // 16 u16
  float* rsum   = (float*)(W + 16);           // 8192 f32 (W+16..16400)
  float* logits = (float*)(W + 16400);        // 16384 f32 (..49168)
  u16* B0 = W + 49168;
  u16* Xp    = B0;                            // encode: [2][8192][768]
  u16* feat3 = B0 + 12582912;                 // [3][8192][512]
  u16* encWb = B0 + 25165824;                 // [2][512][768] bf16 (encode phase)
  u16* wr1   = B0;                            // [256][4608]
  u16* wr2   = B0 + 1179648;                  // [256][2304]
  u16* fused = B0 + 1769472;                  // [8192][512]
  u16* memv  = B0 + 5963776;                  // [8][256][2048]
  u16* memk  = B0 + 10158080;                 // [8][2048][64]
  u16* qk    = B0 + 11206656;                 // [8192][64]
  u16* kraw3 = B0 + 25165824;                 // [3][8192][64]; dead after keyfix
  u16* kvW   = B0 + 26738688;                 // [320][512] bf16; dead after keyval
  float* pf  = (float*)(B0 + 11730944);       // attn: [4][8192][256] f32; dec: [4][256][8192] f32
  u16* dbuf  = memv;
  u16* decf  = memv + 2097152;

  dim3 blk(256);
  detect_k<<<dim3(1), blk, 0, stream>>>((const u16*)encQw, dflag);

  wconv_k<<<dim3(384), blk, 0, stream>>>(encMw, encQw, encWb, dflag);
  patchify_k<<<dim3(512), blk, 0, stream>>>(first, prev, Xp, dflag);
  {
    PA a{encWb, 0, 0, 768, 0, 0, 1, 0};
    PBws b{Xp, 768, (size_t)8192 * 768};
    Epi e{0, feat3, 0, 0, (size_t)8192 * 512, 512, 0, 512,
          encMb, 0, 0, 0, 0, 0, 1.f, 1, 0};
    mgl<PBws><<<dim3(64, 4, 2), blk, 0, stream>>>(a, b, e, 12, 0, dflag);
  }
  patchify_k<<<dim3(256), blk, 0, stream>>>(query, query, Xp, dflag);
  {
    PA a{encWb + 393216, 0, 0, 768, 0, 0, 1, 0};
    PBws b{Xp, 768, 0};
    Epi e{0, feat3 + (size_t)2 * 8192 * 512, 0, 0, 0, 512, 0, 512,
          encQb, 0, 0, 0, 0, 0, 1.f, 1, 0};
    mgl<PBws><<<dim3(64, 4, 1), blk, 0, stream>>>(a, b, e, 12, 0, dflag);
  }

  wreorder_k<<<dim3(4608), blk, 0, stream>>>(dec1W, wr1, 512, 256 * 4608, dflag);
  wreorder_k<<<dim3(2304), blk, 0, stream>>>(dec2W, wr2, 256, 256 * 2304, dflag);
  kvconv_k<<<dim3(80), blk, 0, stream>>>(valW, keyW, kvW, dflag);

  {
    PA a{kvW, 0, 0, 512, 1, 0, 1, 319};
    PBws b{feat3, 512, (size_t)8192 * 512};
    Epi e{1, memv, fused, kraw3, 0, 0, 0, 320,
          valB, keyB, 0, firstM, prevM, 0, 1.f, 0, 0};
    mgl<PBws><<<dim3(64, 3, 3), blk, 0, stream>>>(a, b, e, 8, 0, dflag);
  }
  keyfix_k<<<dim3(32, 3), blk, 0, stream>>>(kraw3, firstM, prevM, memk, qk, rsum, dflag);

  attn_k<<<dim3(128, 4), blk, 0, stream>>>(qk, memk, memv, pf, rsum);
  acomb_k<<<dim3(4096), blk, 0, stream>>>(pf, rsum, fused);

  {
    PA a{wr1, 0, 0, 4608, 0, 0, 1, 0};
    PBc3 b{fused, 512, 9};
    Epi e{2, (u16*)pf, 0, 0, 0, 0, 0, 0,
          0, 0, 0, 0, 0, 0, 1.f, 0, 0};
    mg<PBc3><<<dim3(64, 2, 4), blk, 0, stream>>>(a, b, e, 18, 0, 1152, dflag);
    comb_k<<<dim3(128, 32), blk, 0, stream>>>(pf, dec1B, dbuf, 256, 0, 4, 1, dflag);
  }
  {
    PA a{wr2, 0, 0, 2304, 0, 0, 1, 0};
    PBc3 b{dbuf, 256, 8};
    Epi e{2, (u16*)pf, 0, 0, 0, 0, 0, 0,
          0, 0, 0, 0, 0, 0, 1.f, 0, 0};
    mg<PBc3><<<dim3(64, 2, 4), blk, 0, stream>>>(a, b, e, 9, 0, 576, dflag);
    comb_k<<<dim3(128, 32), blk, 0, stream>>>(pf, dec2B, decf, 256, 0, 4, 1, dflag);
  }

  repcls_k<<<dim3(2048), blk, 0, stream>>>(decf, clsW, clsB, d_out, logits, dflag);
  resize_k<<<dim3(16384), blk, 0, stream>>>(logits, d_out, (size_t)2097152, dflag);
}

// Round 9
// 458.983 us; speedup vs baseline: 1.4569x; 1.0167x over previous
//
#include <hip/hip_runtime.h>
#include <hip/hip_bf16.h>
#include <cstdint>

#define DEV __device__ __forceinline__
typedef __attribute__((ext_vector_type(8))) short short8;
typedef __attribute__((ext_vector_type(4))) float f32x4;
typedef unsigned short u16;

DEV float b2f(u16 u) { union { unsigned int i; float f; } x; x.i = (unsigned)u << 16; return x.f; }
DEV u16 f2b(float f) { __hip_bfloat16 h = __float2bfloat16(f); return *(u16*)&h; }
DEV float rdin(const void* p, size_t i, int isbf) {
  return isbf ? __bfloat162float(((const __hip_bfloat16*)p)[i]) : ((const float*)p)[i];
}
DEV void wrout(void* p, size_t i, float v, int isbf) {
  if (isbf) ((__hip_bfloat16*)p)[i] = __float2bfloat16(v);
  else      ((float*)p)[i] = v;
}
DEV short8 ld8(const void* p, size_t idx, int isbf) {
  if (isbf) return *(const short8*)((const u16*)p + idx);
  const float* f = (const float*)p + idx;
  float4 x = *(const float4*)f, y = *(const float4*)(f + 4);
  short8 r;
  r[0] = f2b(x.x); r[1] = f2b(x.y); r[2] = f2b(x.z); r[3] = f2b(x.w);
  r[4] = f2b(y.x); r[5] = f2b(y.y); r[6] = f2b(y.z); r[7] = f2b(y.w);
  return r;
}
DEV void gl16(const u16* g, u16* l) {
  __builtin_amdgcn_global_load_lds(
      (const __attribute__((address_space(1))) void*)g,
      (__attribute__((address_space(3))) void*)l, 16, 0, 0);
}
DEV void bar() {
  asm volatile("" ::: "memory");
  __builtin_amdgcn_s_barrier();
  asm volatile("" ::: "memory");
}

__global__ __launch_bounds__(256) void detect_k(const u16* w, int* flag) {
  __shared__ int cnt[256];
  int tid = threadIdx.x, c = 0;
  for (int i = tid; i < 4096; i += 256) {
    u16 v = w[i];
    int e = (v >> 7) & 0xFF;
    if (v == 0 || (e >= 0x60 && e <= 0x9F)) c++;
  }
  cnt[tid] = c;
  __syncthreads();
  for (int s = 128; s > 0; s >>= 1) { if (tid < s) cnt[tid] += cnt[tid + s]; __syncthreads(); }
  if (tid == 0) *flag = (cnt[0] > 3600) ? 1 : 0;
}

__global__ __launch_bounds__(256) void patchify_k(const void* F0, const void* F1,
                                                  u16* dst, const int* dflag) {
  int isbf = *dflag;
  int bid = blockIdx.x;
  int z = bid >> 8, rem = bid & 255, b = rem >> 5, y = rem & 31;
  const void* F = z ? F1 : F0;
  int x = threadIdx.x & 31, pj = threadIdx.x >> 5;
  u16* drow = dst + (size_t)(z * 8192 + b * 1024 + y * 32 + x) * 768;
#pragma unroll
  for (int i = 0; i < 6; i++) {
    int pair = i * 8 + pj;
    int c = pair >> 4, ky = pair & 15;
    size_t src = ((size_t)((b * 3 + c) * 512 + y * 16 + ky)) * 512 + x * 16;
    short8 v0 = ld8(F, src, isbf);
    short8 v1 = ld8(F, src + 8, isbf);
    u16* dp = drow + c * 256 + ky * 16;
    *(short8*)dp = v0;
    *(short8*)(dp + 8) = v1;
  }
}

__global__ __launch_bounds__(256) void wconv_k(const void* wm, const void* wq,
                                               u16* dst, const int* dflag) {
  int isbf = *dflag;
  int gi = blockIdx.x * 256 + threadIdx.x;
  size_t e0 = (size_t)gi * 8;
  const void* src = e0 < 393216 ? wm : wq;
  size_t off = e0 < 393216 ? e0 : e0 - 393216;
  *(short8*)&dst[e0] = ld8(src, off, isbf);
}

__global__ __launch_bounds__(256) void kvconv_k(const void* valW, const void* keyW,
                                                u16* dst, const int* dflag) {
  int isbf = *dflag;
  int idx = blockIdx.x * 256 + threadIdx.x;
  size_t e0 = (size_t)idx * 8;
  int row = (int)(e0 >> 9);
  const void* src = row < 256 ? valW : keyW;
  size_t off = row < 256 ? e0 : e0 - (size_t)256 * 512;
  *(short8*)&dst[e0] = ld8(src, off, isbf);
}

struct PA {
  const void* W0; const void* W1; size_t bs; int K; int rowsplit; int zsel; int ws16; int rowmax1;
  DEV short8 l8(int row, int k, int b, int zz, int isbf) const {
    const void* W = W0; int r = row;
    if (zsel && zz == 2) W = W1;
    else if (rowsplit && row >= rowsplit) { W = W1; r = row - rowsplit; if (r > rowmax1) r = rowmax1; }
    return ld8(W, (size_t)b * bs + (size_t)r * K + k, ws16 ? 1 : isbf);
  }
  DEV const u16* ga(int row, int k, int b, int zz) const {
    int r = row; if (rowsplit && r > rowmax1) r = rowmax1;
    return (const u16*)W0 + (size_t)b * bs + (size_t)r * K + k;
  }
};
struct PBws {
  const u16* X; int rs; size_t zs;
  DEV short8 l8(int t, int k, int zz, int) const {
    return *(const short8*)(X + (size_t)zz * zs + (size_t)t * rs + k);
  }
  DEV const u16* ga(int t, int k, int zz) const {
    return X + (size_t)zz * zs + (size_t)t * rs + k;
  }
};
struct PBc3 {
  const u16* X; int C; int shift;
  DEV short8 l8(int t, int k, int, int) const {
    int tap = k >> shift, c0 = k & (C - 1);
    int dy = tap / 3, dx = tap - dy * 3;
    int pos = t & 1023, y = pos >> 5, x = pos & 31;
    int iy = y + dy - 1, ix = x + dx - 1;
    if ((unsigned)iy >= 32u || (unsigned)ix >= 32u) { short8 z = {0,0,0,0,0,0,0,0}; return z; }
    return *(const short8*)(X + (size_t)(((t >> 10) * 1024) + iy * 32 + ix) * C + c0);
  }
};

struct Epi {
  int mode;
  u16 *o16, *o16b, *o16c;
  size_t zs; int ts, moff, mmax;
  const void *bias, *bias2; int bzsel;
  const void *maskA, *maskB;
  const float* rscale;
  float scale; int relu, doexp;
  DEV void store1(int m, int t, int z, float v, int isbf) const {
    if (m >= mmax) return;
    int b = t >> 10, pos = t & 1023;
    if (m < 256) {
      v += rdin(bias, m, isbf);
      if (z < 2) {
        const void* mk = z ? maskB : maskA;
        v *= rdin(mk, ((size_t)(b * 512 + (pos >> 5) * 16) << 9) + (pos & 31) * 16, isbf);
        o16[((size_t)(b * 256 + m)) * 2048 + (size_t)z * 1024 + pos] = f2b(v);
      } else {
        o16b[(size_t)t * 512 + m] = f2b(v);
      }
    } else {
      v += rdin(bias2, m - 256, isbf);
      o16c[((size_t)z * 8192 + t) * 64 + (m - 256)] = f2b(v);
    }
  }
};

DEV void epilogue(const Epi& ep, f32x4 (&acc)[4][4], u16* sh, int isbf, int tid,
                  int col16, int quad, int wm, int wn, int zz, int m0, int n0, int nbase) {
  if (ep.mode == 1) {
#pragma unroll
    for (int mt = 0; mt < 4; mt++)
#pragma unroll
      for (int nt = 0; nt < 4; nt++)
#pragma unroll
        for (int r = 0; r < 4; r++) {
          int m = m0 + wm * 64 + mt * 16 + quad * 4 + r;
          int t = nbase + n0 + wn * 64 + nt * 16 + col16;
          ep.store1(m, t, zz, acc[mt][nt][r], isbf);
        }
    return;
  }
  if (ep.mode == 2) {
    float* pf = (float*)ep.o16;
#pragma unroll
    for (int mt = 0; mt < 4; mt++)
#pragma unroll
      for (int nt = 0; nt < 4; nt++)
#pragma unroll
        for (int r = 0; r < 4; r++) {
          int m = m0 + wm * 64 + mt * 16 + quad * 4 + r;
          int t = nbase + n0 + wn * 64 + nt * 16 + col16;
          pf[((size_t)(zz * 256 + m)) * 8192 + t] = acc[mt][nt][r];
        }
    return;
  }
  u16* T = sh;
  const int TS = 132;
  for (int p = 0; p < 2; p++) {
    __syncthreads();
    if (wn == p) {
#pragma unroll
      for (int mt = 0; mt < 4; mt++)
#pragma unroll
        for (int nt = 0; nt < 4; nt++) {
          int tl = nt * 16 + col16;
#pragma unroll
          for (int r2 = 0; r2 < 2; r2++) {
            int ml = wm * 64 + mt * 16 + quad * 4 + r2 * 2;
            float v0 = acc[mt][nt][r2 * 2] * ep.scale;
            float v1 = acc[mt][nt][r2 * 2 + 1] * ep.scale;
            if (ep.bias) {
              const void* bp = (ep.bzsel && zz == 2) ? ep.bias2 : ep.bias;
              v0 += rdin(bp, m0 + ml, isbf);
              v1 += rdin(bp, m0 + ml + 1, isbf);
            }
            if (ep.relu) { v0 = fmaxf(v0, 0.f); v1 = fmaxf(v1, 0.f); }
            unsigned int pk = (unsigned)f2b(v0) | ((unsigned)f2b(v1) << 16);
            *(unsigned int*)&T[tl * TS + ml] = pk;
          }
        }
    }
    __syncthreads();
    {
      int tl = tid >> 2, seg = tid & 3;
      int tg = nbase + n0 + p * 64 + tl;
      u16* op = ep.o16 + (size_t)zz * ep.zs + (size_t)tg * ep.ts + ep.moff + m0;
#pragma unroll
      for (int i = 0; i < 4; i++) {
        int c8 = seg + i * 4;
        short8 v = *(short8*)&T[tl * TS + c8 * 8];
        *(short8*)&op[c8 * 8] = v;
      }
    }
  }
}

// ---- GL GEMM: 128x128 tile, BK=64, 4 waves; single 32KB LDS buffer.
// NO min-wave bound (rounds 7-8 lesson: forcing 4 blocks/CU clamps VGPR to 64 and
// spills the 64-VGPR accumulator). Natural VGPR ~110-120 <= 128 already allows
// 4 waves/SIMD; LDS 32KB allows 5 blocks/CU.
template <class PB>
__global__ __launch_bounds__(256) void mgl(PA pa, PB pb, Epi ep, int ktiles, int nbase,
                                           const int* dflag) {
  __shared__ u16 sh[16384];
  int isbf = *dflag;
  int tid = threadIdx.x, lane = tid & 63;
  int col16 = lane & 15, quad = lane >> 4;
  int wv = tid >> 6, wm = wv >> 1, wn = wv & 1;
  int zz = blockIdx.z;
  int n0 = blockIdx.x * 128, m0 = blockIdx.y * 128;
  int bA = (nbase + n0) >> 10;

  f32x4 acc[4][4];
#pragma unroll
  for (int mt = 0; mt < 4; mt++)
#pragma unroll
    for (int nt = 0; nt < 4; nt++)
#pragma unroll
      for (int r = 0; r < 4; r++) acc[mt][nt][r] = 0.f;

  int rA[4], lA[4];
#pragma unroll
  for (int g = 0; g < 4; g++) {
    rA[g] = g * 32 + (tid >> 3);
    lA[g] = (tid & 7) ^ (rA[g] & 7);
  }

  for (int kt = 0; kt < ktiles; kt++) {
    int kk = kt * 64;
#pragma unroll
    for (int g = 0; g < 4; g++) {
      gl16(pa.ga(m0 + rA[g], kk + lA[g] * 8, bA, zz), sh + (size_t)(g * 256 + tid) * 8);
      gl16(pb.ga(nbase + n0 + rA[g], kk + lA[g] * 8, zz), sh + 8192 + (size_t)(g * 256 + tid) * 8);
    }
    asm volatile("s_waitcnt vmcnt(0)" ::: "memory");
    bar();
#pragma unroll
    for (int s = 0; s < 2; s++) {
      short8 af[4], bf[4];
      int cs = ((s * 4 + quad) ^ (col16 & 7)) << 3;
#pragma unroll
      for (int mt = 0; mt < 4; mt++)
        af[mt] = *(const short8*)&sh[(wm * 64 + mt * 16 + col16) * 64 + cs];
#pragma unroll
      for (int nt = 0; nt < 4; nt++)
        bf[nt] = *(const short8*)&sh[8192 + (wn * 64 + nt * 16 + col16) * 64 + cs];
#pragma unroll
      for (int mt = 0; mt < 4; mt++)
#pragma unroll
        for (int nt = 0; nt < 4; nt++)
          acc[mt][nt] = __builtin_amdgcn_mfma_f32_16x16x32_bf16(af[mt], bf[nt], acc[mt][nt], 0, 0, 0);
    }
    bar();   // all waves done reading before next issue overwrites
  }

  epilogue(ep, acc, sh, isbf, tid, col16, quad, wm, wn, zz, m0, n0, nbase);
}

// ---- reg-staged GEMM (PBc3): single 32KB LDS + register prefetch; no min-wave bound ----
template <class PB>
__global__ __launch_bounds__(256) void mg(PA pa, PB pb, Epi ep, int ktiles, int nbase,
                                          int ksplit, const int* dflag) {
  __shared__ u16 sh[16384];
  int isbf = *dflag;
  int tid = threadIdx.x, lane = tid & 63;
  int col16 = lane & 15, quad = lane >> 4;
  int wv = tid >> 6, wm = wv >> 1, wn = wv & 1;
  int zz = blockIdx.z;
  int kb = ksplit * zz;
  int n0 = blockIdx.x * 128, m0 = blockIdx.y * 128;
  int bA = (nbase + n0) >> 10;

  f32x4 acc[4][4];
#pragma unroll
  for (int mt = 0; mt < 4; mt++)
#pragma unroll
    for (int nt = 0; nt < 4; nt++)
#pragma unroll
      for (int r = 0; r < 4; r++) acc[mt][nt][r] = 0.f;

  int rA[4], lA[4];
#pragma unroll
  for (int g = 0; g < 4; g++) {
    rA[g] = g * 32 + (tid >> 3);
    lA[g] = (tid & 7) ^ (rA[g] & 7);
  }

  short8 ra[4], rb[4];
#pragma unroll
  for (int g = 0; g < 4; g++) {
    ra[g] = pa.l8(m0 + rA[g], kb + lA[g] * 8, bA, zz, isbf);
    rb[g] = pb.l8(nbase + n0 + rA[g], kb + lA[g] * 8, zz, isbf);
  }

  for (int kt = 0; kt < ktiles; kt++) {
    if (kt) __syncthreads();
#pragma unroll
    for (int g = 0; g < 4; g++) {
      *(short8*)&sh[(size_t)(g * 256 + tid) * 8] = ra[g];
      *(short8*)&sh[8192 + (size_t)(g * 256 + tid) * 8] = rb[g];
    }
    __syncthreads();
    if (kt + 1 < ktiles) {
      int kn = kb + (kt + 1) * 64;
#pragma unroll
      for (int g = 0; g < 4; g++) {
        ra[g] = pa.l8(m0 + rA[g], kn + lA[g] * 8, bA, zz, isbf);
        rb[g] = pb.l8(nbase + n0 + rA[g], kn + lA[g] * 8, zz, isbf);
      }
    }
#pragma unroll
    for (int s = 0; s < 2; s++) {
      short8 af[4], bf[4];
      int cs = ((s * 4 + quad) ^ (col16 & 7)) << 3;
#pragma unroll
      for (int mt = 0; mt < 4; mt++)
        af[mt] = *(const short8*)&sh[(wm * 64 + mt * 16 + col16) * 64 + cs];
#pragma unroll
      for (int nt = 0; nt < 4; nt++)
        bf[nt] = *(const short8*)&sh[8192 + (wn * 64 + nt * 16 + col16) * 64 + cs];
#pragma unroll
      for (int mt = 0; mt < 4; mt++)
#pragma unroll
        for (int nt = 0; nt < 4; nt++)
          acc[mt][nt] = __builtin_amdgcn_mfma_f32_16x16x32_bf16(af[mt], bf[nt], acc[mt][nt], 0, 0, 0);
    }
  }

  epilogue(ep, acc, sh, isbf, tid, col16, quad, wm, wn, zz, m0, n0, nbase);
}

// ---- fused split-KV flash attention; wave-parallel QK; XCD-aware block remap ----
__global__ __launch_bounds__(256) void attn_k(const u16* qk, const u16* memk,
                                              const u16* memv, float* pf, float* rsum) {
  __shared__ u16 sh[28672];            // Qt[64][64] | Kt[64][64] | Vt[256][64] | P[64][64]
  __shared__ float rsl[4][64];
  const int Qt = 0, Kt = 4096, Vt = 8192, Pl = 24576;
  int tid = threadIdx.x, lane = tid & 63;
  int col16 = lane & 15, quad = lane >> 4;
  int wv = tid >> 6;
  int xl = blockIdx.x;
  int x = ((xl & 7) << 4) | (xl >> 3);
  int b = x >> 4, qt = x & 15;
  int q0 = b * 1024 + qt * 64;
  int s = blockIdx.y;
  int kv0 = s * 512;

  rsl[wv][lane] = 0.f;

  int r32 = tid >> 3;
#pragma unroll
  for (int g = 0; g < 2; g++) {
    int row = g * 32 + r32;
    int k8 = (tid & 7) ^ (row & 7);
    gl16(qk + (size_t)(q0 + row) * 64 + k8 * 8, sh + Qt + (size_t)(g * 256 + tid) * 8);
  }
  {
#pragma unroll
    for (int g = 0; g < 2; g++) {
      int row = g * 32 + r32;
      int k8 = (tid & 7) ^ (row & 7);
      gl16(memk + ((size_t)(b * 2048 + kv0 + row)) * 64 + k8 * 8,
           sh + Kt + (size_t)(g * 256 + tid) * 8);
    }
#pragma unroll
    for (int g = 0; g < 8; g++) {
      int row = g * 32 + r32;
      int k8 = (tid & 7) ^ (row & 7);
      gl16(memv + ((size_t)(b * 256 + row)) * 2048 + kv0 + k8 * 8,
           sh + Vt + (size_t)(g * 256 + tid) * 8);
    }
  }
  __syncthreads();

  f32x4 acc_o[4][4];
#pragma unroll
  for (int mt = 0; mt < 4; mt++)
#pragma unroll
    for (int nt = 0; nt < 4; nt++)
#pragma unroll
      for (int r = 0; r < 4; r++) acc_o[mt][nt][r] = 0.f;

  for (int ch = 0; ch < 8; ch++) {
    {
      f32x4 acc_s[4];
#pragma unroll
      for (int nt = 0; nt < 4; nt++)
#pragma unroll
        for (int r = 0; r < 4; r++) acc_s[nt][r] = 0.f;
#pragma unroll
      for (int s2 = 0; s2 < 2; s2++) {
        int cs = ((s2 * 4 + quad) ^ (col16 & 7)) << 3;
        short8 af = *(const short8*)&sh[Kt + (wv * 16 + col16) * 64 + cs];
        short8 bf[4];
#pragma unroll
        for (int nt = 0; nt < 4; nt++)
          bf[nt] = *(const short8*)&sh[Qt + (nt * 16 + col16) * 64 + cs];
#pragma unroll
        for (int nt = 0; nt < 4; nt++)
          acc_s[nt] = __builtin_amdgcn_mfma_f32_16x16x32_bf16(af, bf[nt], acc_s[nt], 0, 0, 0);
      }
#pragma unroll
      for (int nt = 0; nt < 4; nt++) {
        int ql = nt * 16 + col16;
        float tsum = 0.f;
#pragma unroll
        for (int r = 0; r < 4; r++) {
          int kvl = wv * 16 + quad * 4 + r;
          u16 pb = f2b(__expf(0.125f * acc_s[nt][r]));
          tsum += b2f(pb);
          sh[Pl + ql * 64 + (((kvl >> 3) ^ (ql & 7)) << 3) + (kvl & 7)] = pb;
        }
        tsum += __shfl_xor(tsum, 16);
        tsum += __shfl_xor(tsum, 32);
        if (quad == 0) rsl[wv][ql] += tsum;
      }
    }
    __syncthreads();
    if (ch + 1 < 8) {
      int kvc = kv0 + (ch + 1) * 64;
#pragma unroll
      for (int g = 0; g < 2; g++) {
        int row = g * 32 + r32;
        int k8 = (tid & 7) ^ (row & 7);
        gl16(memk + ((size_t)(b * 2048 + kvc + row)) * 64 + k8 * 8,
             sh + Kt + (size_t)(g * 256 + tid) * 8);
      }
    }
#pragma unroll
    for (int s2 = 0; s2 < 2; s2++) {
      short8 af[4], bf[4];
      int cs = ((s2 * 4 + quad) ^ (col16 & 7)) << 3;
#pragma unroll
      for (int mt = 0; mt < 4; mt++)
        af[mt] = *(const short8*)&sh[Vt + (wv * 64 + mt * 16 + col16) * 64 + cs];
#pragma unroll
      for (int nt = 0; nt < 4; nt++)
        bf[nt] = *(const short8*)&sh[Pl + (nt * 16 + col16) * 64 + cs];
#pragma unroll
      for (int mt = 0; mt < 4; mt++)
#pragma unroll
        for (int nt = 0; nt < 4; nt++)
          acc_o[mt][nt] = __builtin_amdgcn_mfma_f32_16x16x32_bf16(af[mt], bf[nt], acc_o[mt][nt], 0, 0, 0);
    }
    __syncthreads();
    if (ch + 1 < 8) {
      int kvc = kv0 + (ch + 1) * 64;
#pragma unroll
      for (int g = 0; g < 8; g++) {
        int row = g * 32 + r32;
        int k8 = (tid & 7) ^ (row & 7);
        gl16(memv + ((size_t)(b * 256 + row)) * 2048 + kvc + k8 * 8,
             sh + Vt + (size_t)(g * 256 + tid) * 8);
      }
    }
    __syncthreads();
  }

#pragma unroll
  for (int mt = 0; mt < 4; mt++)
#pragma unroll
    for (int nt = 0; nt < 4; nt++)
#pragma unroll
      for (int r = 0; r < 4; r++) {
        int c = wv * 64 + mt * 16 + quad * 4 + r;
        int q = nt * 16 + col16;
        pf[((size_t)(s * 8192 + q0 + q)) * 256 + c] = acc_o[mt][nt][r];
      }
  if (tid < 64)
    atomicAdd(&rsum[q0 + tid], rsl[0][tid] + rsl[1][tid] + rsl[2][tid] + rsl[3][tid]);
}

__global__ __launch_bounds__(256) void acomb_k(const float* pf, const float* rsum,
                                               u16* fused) {
  int tid = threadIdx.x;
  int t = blockIdx.x * 2 + (tid >> 7);
  int cp = tid & 127;
  float inv = 1.f / rsum[t];
  float v0 = 0.f, v1 = 0.f;
#pragma unroll
  for (int s = 0; s < 4; s++) {
    const float* p = pf + ((size_t)(s * 8192 + t)) * 256 + cp * 2;
    v0 += p[0]; v1 += p[1];
  }
  unsigned int pk = (unsigned)f2b(v0 * inv) | ((unsigned)f2b(v1 * inv) << 16);
  *(unsigned int*)&fused[(size_t)t * 512 + 256 + cp * 2] = pk;
}

__global__ __launch_bounds__(256) void comb_k(const float* pf, const void* bias,
                                              u16* out, int ts, int moff, int npart,
                                              int relu, const int* dflag) {
  int isbf = *dflag;
  int tid = threadIdx.x;
  int t = blockIdx.x * 64 + (tid & 63);
  int m = blockIdx.y * 8 + ((tid >> 6) << 1);
  float v0 = 0.f, v1 = 0.f;
  for (int p = 0; p < npart; p++) {
    v0 += pf[(size_t)(p * 256 + m) * 8192 + t];
    v1 += pf[(size_t)(p * 256 + m + 1) * 8192 + t];
  }
  if (bias) { v0 += rdin(bias, m, isbf); v1 += rdin(bias, m + 1, isbf); }
  if (relu) { v0 = fmaxf(v0, 0.f); v1 = fmaxf(v1, 0.f); }
  unsigned int pk = (unsigned)f2b(v0) | ((unsigned)f2b(v1) << 16);
  *(unsigned int*)&out[(size_t)t * ts + moff + m] = pk;
}

__global__ __launch_bounds__(256) void wreorder_k(const void* src, u16* dst, int C,
                                                  int total, const int* dflag) {
  int idx = blockIdx.x * 256 + threadIdx.x;
  if (idx >= total) return;
  int isbf = *dflag;
  int nine_c = 9 * C;
  int m = idx / nine_c; int r = idx - m * nine_c;
  int tp = r / C; int c = r - tp * C;
  dst[idx] = f2b(rdin(src, (size_t)(m * C + c) * 9 + tp, isbf));
}

__global__ __launch_bounds__(256) void keyfix_k(const u16* kraw3, const void* mA,
                                                const void* mB, u16* memk, u16* qk,
                                                float* rsum, const int* dflag) {
  int isbf = *dflag;
  int z = blockIdx.y;
  int n = blockIdx.x * 256 + threadIdx.x;
  int b = n >> 10, pos = n & 1023;
  if (z == 0) rsum[n] = 0.f;
  float mv = 1.f;
  if (z == 0) mv = rdin(mA, ((size_t)(b * 512 + (pos >> 5) * 16) << 9) + (pos & 31) * 16, isbf);
  else if (z == 1) mv = rdin(mB, ((size_t)(b * 512 + (pos >> 5) * 16) << 9) + (pos & 31) * 16, isbf);
  const u16* src = kraw3 + ((size_t)z * 8192 + n) * 64;
  float v[64], ss = 0.f;
#pragma unroll
  for (int c = 0; c < 64; c++) { v[c] = b2f(src[c]) * mv; ss += v[c] * v[c]; }
  float inv = 1.f / fmaxf(sqrtf(ss), 1e-12f);
  u16* dst = (z < 2) ? memk + (size_t)(b * 2048 + z * 1024 + pos) * 64 : qk + (size_t)n * 64;
#pragma unroll
  for (int c = 0; c < 64; c++) dst[c] = f2b(v[c] * inv);
}

__global__ __launch_bounds__(256) void repcls_k(const u16* decf, const void* cwgt,
                                                const void* cbias, void* out_rep,
                                                float* logits, const int* dflag) {
  int isbf = *dflag;
  int tid = threadIdx.x, lane = tid & 63, wv = tid >> 6;
  int tok = blockIdx.x * 4 + wv;
  int b = tok >> 10, pos = tok & 1023;
  const u16* src = decf + (size_t)tok * 256;
  int c0 = lane * 4;
  float v[4], ss = 0.f, a0 = 0.f, a1 = 0.f;
#pragma unroll
  for (int j = 0; j < 4; j++) {
    float x = b2f(src[c0 + j]);
    v[j] = x; ss += x * x;
    a0 = fmaf(x, rdin(cwgt, c0 + j, isbf), a0);
    a1 = fmaf(x, rdin(cwgt, 256 + c0 + j, isbf), a1);
  }
#pragma unroll
  for (int off = 32; off > 0; off >>= 1) {
    ss += __shfl_down(ss, off); a0 += __shfl_down(a0, off); a1 += __shfl_down(a1, off);
  }
  ss = __shfl(ss, 0); a0 = __shfl(a0, 0); a1 = __shfl(a1, 0);
  float inv = 1.f / fmaxf(sqrtf(ss), 1e-12f);
#pragma unroll
  for (int j = 0; j < 4; j++)
    wrout(out_rep, ((size_t)(b * 256 + c0 + j) << 10) + pos, v[j] * inv, isbf);
  if (lane == 0) {
    logits[((size_t)(b * 2) << 10) + pos]     = a0 + rdin(cbias, 0, isbf);
    logits[((size_t)(b * 2 + 1) << 10) + pos] = a1 + rdin(cbias, 1, isbf);
  }
}

__global__ __launch_bounds__(256) void resize_k(const float* logits, void* out,
                                                size_t ebase, const int* dflag) {
  int isbf = *dflag;
  int idx = blockIdx.x * 256 + threadIdx.x;
  int ox = idx & 511, oy = (idx >> 9) & 511, c = (idx >> 18) & 1, b = idx >> 19;
  float fy = (oy + 0.5f) * 0.0625f - 0.5f;
  float fx = (ox + 0.5f) * 0.0625f - 0.5f;
  int y0 = (int)floorf(fy), x0 = (int)floorf(fx);
  float wy = fy - y0, wx = fx - x0;
  int y0c = max(y0, 0), y1c = min(y0 + 1, 31);
  int x0c = max(x0, 0), x1c = min(x0 + 1, 31);
  const float* L = logits + ((size_t)(b * 2 + c) << 10);
  float v00 = L[y0c * 32 + x0c], v01 = L[y0c * 32 + x1c];
  float v10 = L[y1c * 32 + x0c], v11 = L[y1c * 32 + x1c];
  float v = (1.f - wy) * ((1.f - wx) * v00 + wx * v01) + wy * ((1.f - wx) * v10 + wx * v11);
  wrout(out, ebase + (size_t)idx, v, isbf);
}

extern "C" void kernel_launch(void* const* d_in, const int* in_sizes, int n_in,
                              void* d_out, int out_size, void* d_ws, size_t ws_size,
                              hipStream_t stream) {
  const void* query  = d_in[0];  const void* prev   = d_in[1];
  const void* prevM  = d_in[2];  const void* first  = d_in[3];
  const void* firstM = d_in[4];  const void* encQw  = d_in[5];
  const void* encQb  = d_in[6];  const void* encMw  = d_in[7];
  const void* encMb  = d_in[8];  const void* keyW   = d_in[9];
  const void* keyB   = d_in[10]; const void* valW   = d_in[11];
  const void* valB   = d_in[12]; const void* dec1W  = d_in[13];
  const void* dec1B  = d_in[14]; const void* dec2W  = d_in[15];
  const void* dec2B  = d_in[16]; const void* clsW   = d_in[17];
  const void* clsB   = d_in[18];

  u16* W = (u16*)d_ws;
  int* dflag = (int*)W;                       // 16 u16
  float* rsum   = (float*)(W + 16);           // 8192 f32 (W+16..16400)
  float* logits = (float*)(W + 16400);        // 16384 f32 (..49168)
  u16* B0 = W + 49168;
  u16* Xp    = B0;                            // encode: [2][8192][768]
  u16* feat3 = B0 + 12582912;                 // [3][8192][512]
  u16* encWb = B0 + 25165824;                 // [2][512][768] bf16 (encode phase)
  u16* wr1   = B0;                            // [256][4608]
  u16* wr2   = B0 + 1179648;                  // [256][2304]
  u16* fused = B0 + 1769472;                  // [8192][512]
  u16* memv  = B0 + 5963776;                  // [8][256][2048]
  u16* memk  = B0 + 10158080;                 // [8][2048][64]
  u16* qk    = B0 + 11206656;                 // [8192][64]
  u16* kraw3 = B0 + 25165824;                 // [3][8192][64]; dead after keyfix
  u16* kvW   = B0 + 26738688;                 // [320][512] bf16; dead after keyval
  float* pf  = (float*)(B0 + 11730944);       // attn: [4][8192][256] f32; dec: [4][256][8192] f32
  u16* dbuf  = memv;
  u16* decf  = memv + 2097152;

  dim3 blk(256);
  detect_k<<<dim3(1), blk, 0, stream>>>((const u16*)encQw, dflag);

  wconv_k<<<dim3(384), blk, 0, stream>>>(encMw, encQw, encWb, dflag);
  patchify_k<<<dim3(512), blk, 0, stream>>>(first, prev, Xp, dflag);
  {
    PA a{encWb, 0, 0, 768, 0, 0, 1, 0};
    PBws b{Xp, 768, (size_t)8192 * 768};
    Epi e{0, feat3, 0, 0, (size_t)8192 * 512, 512, 0, 512,
          encMb, 0, 0, 0, 0, 0, 1.f, 1, 0};
    mgl<PBws><<<dim3(64, 4, 2), blk, 0, stream>>>(a, b, e, 12, 0, dflag);
  }
  patchify_k<<<dim3(256), blk, 0, stream>>>(query, query, Xp, dflag);
  {
    PA a{encWb + 393216, 0, 0, 768, 0, 0, 1, 0};
    PBws b{Xp, 768, 0};
    Epi e{0, feat3 + (size_t)2 * 8192 * 512, 0, 0, 0, 512, 0, 512,
          encQb, 0, 0, 0, 0, 0, 1.f, 1, 0};
    mgl<PBws><<<dim3(64, 4, 1), blk, 0, stream>>>(a, b, e, 12, 0, dflag);
  }

  wreorder_k<<<dim3(4608), blk, 0, stream>>>(dec1W, wr1, 512, 256 * 4608, dflag);
  wreorder_k<<<dim3(2304), blk, 0, stream>>>(dec2W, wr2, 256, 256 * 2304, dflag);
  kvconv_k<<<dim3(80), blk, 0, stream>>>(valW, keyW, kvW, dflag);

  {
    PA a{kvW, 0, 0, 512, 1, 0, 1, 319};
    PBws b{feat3, 512, (size_t)8192 * 512};
    Epi e{1, memv, fused, kraw3, 0, 0, 0, 320,
          valB, keyB, 0, firstM, prevM, 0, 1.f, 0, 0};
    mgl<PBws><<<dim3(64, 3, 3), blk, 0, stream>>>(a, b, e, 8, 0, dflag);
  }
  keyfix_k<<<dim3(32, 3), blk, 0, stream>>>(kraw3, firstM, prevM, memk, qk, rsum, dflag);

  attn_k<<<dim3(128, 4), blk, 0, stream>>>(qk, memk, memv, pf, rsum);
  acomb_k<<<dim3(4096), blk, 0, stream>>>(pf, rsum, fused);

  {
    PA a{wr1, 0, 0, 4608, 0, 0, 1, 0};
    PBc3 b{fused, 512, 9};
    Epi e{2, (u16*)pf, 0, 0, 0, 0, 0, 0,
          0, 0, 0, 0, 0, 0, 1.f, 0, 0};
    mg<PBc3><<<dim3(64, 2, 4), blk, 0, stream>>>(a, b, e, 18, 0, 1152, dflag);
    comb_k<<<dim3(128, 32), blk, 0, stream>>>(pf, dec1B, dbuf, 256, 0, 4, 1, dflag);
  }
  {
    PA a{wr2, 0, 0, 2304, 0, 0, 1, 0};
    PBc3 b{dbuf, 256, 8};
    Epi e{2, (u16*)pf, 0, 0, 0, 0, 0, 0,
          0, 0, 0, 0, 0, 0, 1.f, 0, 0};
    mg<PBc3><<<dim3(64, 2, 4), blk, 0, stream>>>(a, b, e, 9, 0, 576, dflag);
    comb_k<<<dim3(128, 32), blk, 0, stream>>>(pf, dec2B, decf, 256, 0, 4, 1, dflag);
  }

  repcls_k<<<dim3(2048), blk, 0, stream>>>(decf, clsW, clsB, d_out, logits, dflag);
  resize_k<<<dim3(16384), blk, 0, stream>>>(logits, d_out, (size_t)2097152, dflag);
}

// Round 10
// 434.707 us; speedup vs baseline: 1.5383x; 1.0558x over previous
//
#include <hip/hip_runtime.h>
#include <hip/hip_bf16.h>
#include <cstdint>

#define DEV __device__ __forceinline__
typedef __attribute__((ext_vector_type(8))) short short8;
typedef __attribute__((ext_vector_type(4))) float f32x4;
typedef unsigned short u16;

DEV float b2f(u16 u) { union { unsigned int i; float f; } x; x.i = (unsigned)u << 16; return x.f; }
DEV u16 f2b(float f) { __hip_bfloat16 h = __float2bfloat16(f); return *(u16*)&h; }
DEV float rdin(const void* p, size_t i, int isbf) {
  return isbf ? __bfloat162float(((const __hip_bfloat16*)p)[i]) : ((const float*)p)[i];
}
DEV void wrout(void* p, size_t i, float v, int isbf) {
  if (isbf) ((__hip_bfloat16*)p)[i] = __float2bfloat16(v);
  else      ((float*)p)[i] = v;
}
DEV short8 ld8(const void* p, size_t idx, int isbf) {
  if (isbf) return *(const short8*)((const u16*)p + idx);
  const float* f = (const float*)p + idx;
  float4 x = *(const float4*)f, y = *(const float4*)(f + 4);
  short8 r;
  r[0] = f2b(x.x); r[1] = f2b(x.y); r[2] = f2b(x.z); r[3] = f2b(x.w);
  r[4] = f2b(y.x); r[5] = f2b(y.y); r[6] = f2b(y.z); r[7] = f2b(y.w);
  return r;
}
DEV void gl16(const u16* g, u16* l) {
  __builtin_amdgcn_global_load_lds(
      (const __attribute__((address_space(1))) void*)g,
      (__attribute__((address_space(3))) void*)l, 16, 0, 0);
}
DEV void bar() {
  asm volatile("" ::: "memory");
  __builtin_amdgcn_s_barrier();
  asm volatile("" ::: "memory");
}

__global__ __launch_bounds__(256) void detect_k(const u16* w, int* flag) {
  __shared__ int cnt[256];
  int tid = threadIdx.x, c = 0;
  for (int i = tid; i < 4096; i += 256) {
    u16 v = w[i];
    int e = (v >> 7) & 0xFF;
    if (v == 0 || (e >= 0x60 && e <= 0x9F)) c++;
  }
  cnt[tid] = c;
  __syncthreads();
  for (int s = 128; s > 0; s >>= 1) { if (tid < s) cnt[tid] += cnt[tid + s]; __syncthreads(); }
  if (tid == 0) *flag = (cnt[0] > 3600) ? 1 : 0;
}

// fused prep1: blocks 0..511 = patchify(first,prev) ; 512..895 = wconv
__global__ __launch_bounds__(256) void prep1_k(const void* F0, const void* F1,
                                               u16* Xp, const void* wm, const void* wq,
                                               u16* encWb, const int* dflag) {
  int isbf = *dflag;
  int bid = blockIdx.x;
  if (bid < 512) {
    int z = bid >> 8, rem = bid & 255, b = rem >> 5, y = rem & 31;
    const void* F = z ? F1 : F0;
    int x = threadIdx.x & 31, pj = threadIdx.x >> 5;
    u16* drow = Xp + (size_t)(z * 8192 + b * 1024 + y * 32 + x) * 768;
#pragma unroll
    for (int i = 0; i < 6; i++) {
      int pair = i * 8 + pj;
      int c = pair >> 4, ky = pair & 15;
      size_t src = ((size_t)((b * 3 + c) * 512 + y * 16 + ky)) * 512 + x * 16;
      short8 v0 = ld8(F, src, isbf);
      short8 v1 = ld8(F, src + 8, isbf);
      u16* dp = drow + c * 256 + ky * 16;
      *(short8*)dp = v0;
      *(short8*)(dp + 8) = v1;
    }
  } else {
    int gi = (bid - 512) * 256 + threadIdx.x;
    size_t e0 = (size_t)gi * 8;
    const void* src = e0 < 393216 ? wm : wq;
    size_t off = e0 < 393216 ? e0 : e0 - 393216;
    *(short8*)&encWb[e0] = ld8(src, off, isbf);
  }
}

// patchify query only (second pass)
__global__ __launch_bounds__(256) void patchify_k(const void* F0, u16* dst,
                                                  const int* dflag) {
  int isbf = *dflag;
  int rem = blockIdx.x, b = rem >> 5, y = rem & 31;
  int x = threadIdx.x & 31, pj = threadIdx.x >> 5;
  u16* drow = dst + (size_t)(b * 1024 + y * 32 + x) * 768;
#pragma unroll
  for (int i = 0; i < 6; i++) {
    int pair = i * 8 + pj;
    int c = pair >> 4, ky = pair & 15;
    size_t src = ((size_t)((b * 3 + c) * 512 + y * 16 + ky)) * 512 + x * 16;
    short8 v0 = ld8(F0, src, isbf);
    short8 v1 = ld8(F0, src + 8, isbf);
    u16* dp = drow + c * 256 + ky * 16;
    *(short8*)dp = v0;
    *(short8*)(dp + 8) = v1;
  }
}

// fused prep2: blocks 0..4607 wreorder(dec1W,C=512); 4608..6911 wreorder(dec2W,C=256);
// 6912..6991 kvconv
__global__ __launch_bounds__(256) void prep2_k(const void* dec1W, u16* wr1,
                                               const void* dec2W, u16* wr2,
                                               const void* valW, const void* keyW,
                                               u16* kvW, const int* dflag) {
  int isbf = *dflag;
  int bid = blockIdx.x;
  if (bid < 6912) {
    const void* src; u16* dst; int C; int idx;
    if (bid < 4608) { src = dec1W; dst = wr1; C = 512; idx = bid * 256 + threadIdx.x; }
    else            { src = dec2W; dst = wr2; C = 256; idx = (bid - 4608) * 256 + threadIdx.x; }
    int nine_c = 9 * C;
    int m = idx / nine_c; int r = idx - m * nine_c;
    int tp = r / C; int c = r - tp * C;
    dst[idx] = f2b(rdin(src, (size_t)(m * C + c) * 9 + tp, isbf));
  } else {
    int idx = (bid - 6912) * 256 + threadIdx.x;
    size_t e0 = (size_t)idx * 8;
    int row = (int)(e0 >> 9);
    const void* src = row < 256 ? valW : keyW;
    size_t off = row < 256 ? e0 : e0 - (size_t)256 * 512;
    *(short8*)&kvW[e0] = ld8(src, off, isbf);
  }
}

struct PA {
  const void* W0; const void* W1; size_t bs; int K; int rowsplit; int zsel; int ws16; int rowmax1;
  DEV short8 l8(int row, int k, int b, int zz, int isbf) const {
    const void* W = W0; int r = row;
    if (zsel && zz == 2) W = W1;
    else if (rowsplit && row >= rowsplit) { W = W1; r = row - rowsplit; if (r > rowmax1) r = rowmax1; }
    return ld8(W, (size_t)b * bs + (size_t)r * K + k, ws16 ? 1 : isbf);
  }
  DEV const u16* ga(int row, int k, int b, int zz) const {
    int r = row; if (rowsplit && r > rowmax1) r = rowmax1;
    return (const u16*)W0 + (size_t)b * bs + (size_t)r * K + k;
  }
};
struct PBws {
  const u16* X; int rs; size_t zs;
  DEV short8 l8(int t, int k, int zz, int) const {
    return *(const short8*)(X + (size_t)zz * zs + (size_t)t * rs + k);
  }
  DEV const u16* ga(int t, int k, int zz) const {
    return X + (size_t)zz * zs + (size_t)t * rs + k;
  }
};
struct PBc3 {
  const u16* X; int C; int shift;
  DEV short8 l8(int t, int k, int, int) const {
    int tap = k >> shift, c0 = k & (C - 1);
    int dy = tap / 3, dx = tap - dy * 3;
    int pos = t & 1023, y = pos >> 5, x = pos & 31;
    int iy = y + dy - 1, ix = x + dx - 1;
    if ((unsigned)iy >= 32u || (unsigned)ix >= 32u) { short8 z = {0,0,0,0,0,0,0,0}; return z; }
    return *(const short8*)(X + (size_t)(((t >> 10) * 1024) + iy * 32 + ix) * C + c0);
  }
};

struct Epi {
  int mode;
  u16 *o16, *o16b, *o16c;
  size_t zs; int ts, moff, mmax;
  const void *bias, *bias2; int bzsel;
  const void *maskA, *maskB;
  const float* rscale;
  float scale; int relu, doexp;
  DEV void store1(int m, int t, int z, float v, int isbf) const {
    if (m >= mmax) return;
    int b = t >> 10, pos = t & 1023;
    if (m < 256) {
      v += rdin(bias, m, isbf);
      if (z < 2) {
        const void* mk = z ? maskB : maskA;
        v *= rdin(mk, ((size_t)(b * 512 + (pos >> 5) * 16) << 9) + (pos & 31) * 16, isbf);
        o16[((size_t)(b * 256 + m)) * 2048 + (size_t)z * 1024 + pos] = f2b(v);
      } else {
        o16b[(size_t)t * 512 + m] = f2b(v);
      }
    } else {
      v += rdin(bias2, m - 256, isbf);
      o16c[((size_t)z * 8192 + t) * 64 + (m - 256)] = f2b(v);
    }
  }
};

DEV void epilogue(const Epi& ep, f32x4 (&acc)[4][4], u16* sh, int isbf, int tid,
                  int col16, int quad, int wm, int wn, int zz, int m0, int n0, int nbase) {
  if (ep.mode == 1) {
#pragma unroll
    for (int mt = 0; mt < 4; mt++)
#pragma unroll
      for (int nt = 0; nt < 4; nt++)
#pragma unroll
        for (int r = 0; r < 4; r++) {
          int m = m0 + wm * 64 + mt * 16 + quad * 4 + r;
          int t = nbase + n0 + wn * 64 + nt * 16 + col16;
          ep.store1(m, t, zz, acc[mt][nt][r], isbf);
        }
    return;
  }
  if (ep.mode == 2) {
    float* pf = (float*)ep.o16;
#pragma unroll
    for (int mt = 0; mt < 4; mt++)
#pragma unroll
      for (int nt = 0; nt < 4; nt++)
#pragma unroll
        for (int r = 0; r < 4; r++) {
          int m = m0 + wm * 64 + mt * 16 + quad * 4 + r;
          int t = nbase + n0 + wn * 64 + nt * 16 + col16;
          pf[((size_t)(zz * 256 + m)) * 8192 + t] = acc[mt][nt][r];
        }
    return;
  }
  u16* T = sh;
  const int TS = 132;
  for (int p = 0; p < 2; p++) {
    __syncthreads();
    if (wn == p) {
#pragma unroll
      for (int mt = 0; mt < 4; mt++)
#pragma unroll
        for (int nt = 0; nt < 4; nt++) {
          int tl = nt * 16 + col16;
#pragma unroll
          for (int r2 = 0; r2 < 2; r2++) {
            int ml = wm * 64 + mt * 16 + quad * 4 + r2 * 2;
            float v0 = acc[mt][nt][r2 * 2] * ep.scale;
            float v1 = acc[mt][nt][r2 * 2 + 1] * ep.scale;
            if (ep.bias) {
              const void* bp = (ep.bzsel && zz == 2) ? ep.bias2 : ep.bias;
              v0 += rdin(bp, m0 + ml, isbf);
              v1 += rdin(bp, m0 + ml + 1, isbf);
            }
            if (ep.relu) { v0 = fmaxf(v0, 0.f); v1 = fmaxf(v1, 0.f); }
            unsigned int pk = (unsigned)f2b(v0) | ((unsigned)f2b(v1) << 16);
            *(unsigned int*)&T[tl * TS + ml] = pk;
          }
        }
    }
    __syncthreads();
    {
      int tl = tid >> 2, seg = tid & 3;
      int tg = nbase + n0 + p * 64 + tl;
      u16* op = ep.o16 + (size_t)zz * ep.zs + (size_t)tg * ep.ts + ep.moff + m0;
#pragma unroll
      for (int i = 0; i < 4; i++) {
        int c8 = seg + i * 4;
        short8 v = *(short8*)&T[tl * TS + c8 * 8];
        *(short8*)&op[c8 * 8] = v;
      }
    }
  }
}

// ---- GL GEMM: 128x128 tile, BK=64, 4 waves; double-buffered global_load_lds +
// counted vmcnt (round-6 proven config; plain bounds — min-wave bound spills acc).
template <class PB>
__global__ __launch_bounds__(256) void mgl(PA pa, PB pb, Epi ep, int ktiles, int nbase,
                                           const int* dflag) {
  __shared__ u16 sh[32768];
  int isbf = *dflag;
  int tid = threadIdx.x, lane = tid & 63;
  int col16 = lane & 15, quad = lane >> 4;
  int wv = tid >> 6, wm = wv >> 1, wn = wv & 1;
  int zz = blockIdx.z;
  int n0 = blockIdx.x * 128, m0 = blockIdx.y * 128;
  int bA = (nbase + n0) >> 10;

  f32x4 acc[4][4];
#pragma unroll
  for (int mt = 0; mt < 4; mt++)
#pragma unroll
    for (int nt = 0; nt < 4; nt++)
#pragma unroll
      for (int r = 0; r < 4; r++) acc[mt][nt][r] = 0.f;

  int rA[4], lA[4];
#pragma unroll
  for (int g = 0; g < 4; g++) {
    rA[g] = g * 32 + (tid >> 3);
    lA[g] = (tid & 7) ^ (rA[g] & 7);
  }

  auto issue = [&](int kt) {
    int kk = kt * 64;
    u16* base = sh + ((kt & 1) << 14);
#pragma unroll
    for (int g = 0; g < 4; g++) {
      gl16(pa.ga(m0 + rA[g], kk + lA[g] * 8, bA, zz), base + (size_t)(g * 256 + tid) * 8);
      gl16(pb.ga(nbase + n0 + rA[g], kk + lA[g] * 8, zz), base + 8192 + (size_t)(g * 256 + tid) * 8);
    }
  };
  issue(0);

  for (int kt = 0; kt < ktiles; kt++) {
    const u16* As = sh + ((kt & 1) << 14);
    const u16* Bs = As + 8192;
    if (kt + 1 < ktiles) {
      issue(kt + 1);
      asm volatile("s_waitcnt vmcnt(8)" ::: "memory");
    } else {
      asm volatile("s_waitcnt vmcnt(0)" ::: "memory");
    }
    bar();
#pragma unroll
    for (int s = 0; s < 2; s++) {
      short8 af[4], bf[4];
      int cs = ((s * 4 + quad) ^ (col16 & 7)) << 3;
#pragma unroll
      for (int mt = 0; mt < 4; mt++)
        af[mt] = *(const short8*)&As[(wm * 64 + mt * 16 + col16) * 64 + cs];
#pragma unroll
      for (int nt = 0; nt < 4; nt++)
        bf[nt] = *(const short8*)&Bs[(wn * 64 + nt * 16 + col16) * 64 + cs];
#pragma unroll
      for (int mt = 0; mt < 4; mt++)
#pragma unroll
        for (int nt = 0; nt < 4; nt++)
          acc[mt][nt] = __builtin_amdgcn_mfma_f32_16x16x32_bf16(af[mt], bf[nt], acc[mt][nt], 0, 0, 0);
    }
    bar();
  }

  epilogue(ep, acc, sh, isbf, tid, col16, quad, wm, wn, zz, m0, n0, nbase);
}

// ---- reg-staged GEMM (PBc3): double-buffered LDS, plain bounds (round-6 proven) ----
template <class PB>
__global__ __launch_bounds__(256) void mg(PA pa, PB pb, Epi ep, int ktiles, int nbase,
                                          int ksplit, const int* dflag) {
  __shared__ u16 sh[32768];
  int isbf = *dflag;
  int tid = threadIdx.x, lane = tid & 63;
  int col16 = lane & 15, quad = lane >> 4;
  int wv = tid >> 6, wm = wv >> 1, wn = wv & 1;
  int zz = blockIdx.z;
  int kb = ksplit * zz;
  int n0 = blockIdx.x * 128, m0 = blockIdx.y * 128;
  int bA = (nbase + n0) >> 10;

  f32x4 acc[4][4];
#pragma unroll
  for (int mt = 0; mt < 4; mt++)
#pragma unroll
    for (int nt = 0; nt < 4; nt++)
#pragma unroll
      for (int r = 0; r < 4; r++) acc[mt][nt][r] = 0.f;

  int rA[4], lA[4];
#pragma unroll
  for (int g = 0; g < 4; g++) {
    rA[g] = g * 32 + (tid >> 3);
    lA[g] = (tid & 7) ^ (rA[g] & 7);
  }

  short8 ra[4], rb[4];
#pragma unroll
  for (int g = 0; g < 4; g++) {
    ra[g] = pa.l8(m0 + rA[g], kb + lA[g] * 8, bA, zz, isbf);
    rb[g] = pb.l8(nbase + n0 + rA[g], kb + lA[g] * 8, zz, isbf);
  }
#pragma unroll
  for (int g = 0; g < 4; g++) {
    *(short8*)&sh[(size_t)(g * 256 + tid) * 8] = ra[g];
    *(short8*)&sh[8192 + (size_t)(g * 256 + tid) * 8] = rb[g];
  }
  __syncthreads();

  for (int kt = 0; kt < ktiles; kt++) {
    const u16* As = sh + ((kt & 1) ? 16384 : 0);
    const u16* Bs = As + 8192;
    bool more = (kt + 1 < ktiles);
    if (more) {
      int kn = kb + (kt + 1) * 64;
#pragma unroll
      for (int g = 0; g < 4; g++) {
        ra[g] = pa.l8(m0 + rA[g], kn + lA[g] * 8, bA, zz, isbf);
        rb[g] = pb.l8(nbase + n0 + rA[g], kn + lA[g] * 8, zz, isbf);
      }
    }
#pragma unroll
    for (int s = 0; s < 2; s++) {
      short8 af[4], bf[4];
      int cs = ((s * 4 + quad) ^ (col16 & 7)) << 3;
#pragma unroll
      for (int mt = 0; mt < 4; mt++)
        af[mt] = *(const short8*)&As[(wm * 64 + mt * 16 + col16) * 64 + cs];
#pragma unroll
      for (int nt = 0; nt < 4; nt++)
        bf[nt] = *(const short8*)&Bs[(wn * 64 + nt * 16 + col16) * 64 + cs];
#pragma unroll
      for (int mt = 0; mt < 4; mt++)
#pragma unroll
        for (int nt = 0; nt < 4; nt++)
          acc[mt][nt] = __builtin_amdgcn_mfma_f32_16x16x32_bf16(af[mt], bf[nt], acc[mt][nt], 0, 0, 0);
    }
    if (more) {
      u16* An = sh + (!(kt & 1) ? 16384 : 0);
#pragma unroll
      for (int g = 0; g < 4; g++) {
        *(short8*)&An[(size_t)(g * 256 + tid) * 8] = ra[g];
        *(short8*)&An[8192 + (size_t)(g * 256 + tid) * 8] = rb[g];
      }
      __syncthreads();
    }
  }

  epilogue(ep, acc, sh, isbf, tid, col16, quad, wm, wn, zz, m0, n0, nbase);
}

// ---- fused split-KV flash attention; wave-parallel QK; XCD-aware block remap ----
__global__ __launch_bounds__(256) void attn_k(const u16* qk, const u16* memk,
                                              const u16* memv, float* pf, float* rsum) {
  __shared__ u16 sh[28672];            // Qt[64][64] | Kt[64][64] | Vt[256][64] | P[64][64]
  __shared__ float rsl[4][64];
  const int Qt = 0, Kt = 4096, Vt = 8192, Pl = 24576;
  int tid = threadIdx.x, lane = tid & 63;
  int col16 = lane & 15, quad = lane >> 4;
  int wv = tid >> 6;
  int xl = blockIdx.x;
  int x = ((xl & 7) << 4) | (xl >> 3);
  int b = x >> 4, qt = x & 15;
  int q0 = b * 1024 + qt * 64;
  int s = blockIdx.y;
  int kv0 = s * 512;

  rsl[wv][lane] = 0.f;

  int r32 = tid >> 3;
#pragma unroll
  for (int g = 0; g < 2; g++) {
    int row = g * 32 + r32;
    int k8 = (tid & 7) ^ (row & 7);
    gl16(qk + (size_t)(q0 + row) * 64 + k8 * 8, sh + Qt + (size_t)(g * 256 + tid) * 8);
  }
  {
#pragma unroll
    for (int g = 0; g < 2; g++) {
      int row = g * 32 + r32;
      int k8 = (tid & 7) ^ (row & 7);
      gl16(memk + ((size_t)(b * 2048 + kv0 + row)) * 64 + k8 * 8,
           sh + Kt + (size_t)(g * 256 + tid) * 8);
    }
#pragma unroll
    for (int g = 0; g < 8; g++) {
      int row = g * 32 + r32;
      int k8 = (tid & 7) ^ (row & 7);
      gl16(memv + ((size_t)(b * 256 + row)) * 2048 + kv0 + k8 * 8,
           sh + Vt + (size_t)(g * 256 + tid) * 8);
    }
  }
  __syncthreads();

  f32x4 acc_o[4][4];
#pragma unroll
  for (int mt = 0; mt < 4; mt++)
#pragma unroll
    for (int nt = 0; nt < 4; nt++)
#pragma unroll
      for (int r = 0; r < 4; r++) acc_o[mt][nt][r] = 0.f;

  for (int ch = 0; ch < 8; ch++) {
    {
      f32x4 acc_s[4];
#pragma unroll
      for (int nt = 0; nt < 4; nt++)
#pragma unroll
        for (int r = 0; r < 4; r++) acc_s[nt][r] = 0.f;
#pragma unroll
      for (int s2 = 0; s2 < 2; s2++) {
        int cs = ((s2 * 4 + quad) ^ (col16 & 7)) << 3;
        short8 af = *(const short8*)&sh[Kt + (wv * 16 + col16) * 64 + cs];
        short8 bf[4];
#pragma unroll
        for (int nt = 0; nt < 4; nt++)
          bf[nt] = *(const short8*)&sh[Qt + (nt * 16 + col16) * 64 + cs];
#pragma unroll
        for (int nt = 0; nt < 4; nt++)
          acc_s[nt] = __builtin_amdgcn_mfma_f32_16x16x32_bf16(af, bf[nt], acc_s[nt], 0, 0, 0);
      }
#pragma unroll
      for (int nt = 0; nt < 4; nt++) {
        int ql = nt * 16 + col16;
        float tsum = 0.f;
#pragma unroll
        for (int r = 0; r < 4; r++) {
          int kvl = wv * 16 + quad * 4 + r;
          u16 pb = f2b(__expf(0.125f * acc_s[nt][r]));
          tsum += b2f(pb);
          sh[Pl + ql * 64 + (((kvl >> 3) ^ (ql & 7)) << 3) + (kvl & 7)] = pb;
        }
        tsum += __shfl_xor(tsum, 16);
        tsum += __shfl_xor(tsum, 32);
        if (quad == 0) rsl[wv][ql] += tsum;
      }
    }
    __syncthreads();
    if (ch + 1 < 8) {
      int kvc = kv0 + (ch + 1) * 64;
#pragma unroll
      for (int g = 0; g < 2; g++) {
        int row = g * 32 + r32;
        int k8 = (tid & 7) ^ (row & 7);
        gl16(memk + ((size_t)(b * 2048 + kvc + row)) * 64 + k8 * 8,
             sh + Kt + (size_t)(g * 256 + tid) * 8);
      }
    }
#pragma unroll
    for (int s2 = 0; s2 < 2; s2++) {
      short8 af[4], bf[4];
      int cs = ((s2 * 4 + quad) ^ (col16 & 7)) << 3;
#pragma unroll
      for (int mt = 0; mt < 4; mt++)
        af[mt] = *(const short8*)&sh[Vt + (wv * 64 + mt * 16 + col16) * 64 + cs];
#pragma unroll
      for (int nt = 0; nt < 4; nt++)
        bf[nt] = *(const short8*)&sh[Pl + (nt * 16 + col16) * 64 + cs];
#pragma unroll
      for (int mt = 0; mt < 4; mt++)
#pragma unroll
        for (int nt = 0; nt < 4; nt++)
          acc_o[mt][nt] = __builtin_amdgcn_mfma_f32_16x16x32_bf16(af[mt], bf[nt], acc_o[mt][nt], 0, 0, 0);
    }
    __syncthreads();
    if (ch + 1 < 8) {
      int kvc = kv0 + (ch + 1) * 64;
#pragma unroll
      for (int g = 0; g < 8; g++) {
        int row = g * 32 + r32;
        int k8 = (tid & 7) ^ (row & 7);
        gl16(memv + ((size_t)(b * 256 + row)) * 2048 + kvc + k8 * 8,
             sh + Vt + (size_t)(g * 256 + tid) * 8);
      }
    }
    __syncthreads();
  }

#pragma unroll
  for (int mt = 0; mt < 4; mt++)
#pragma unroll
    for (int nt = 0; nt < 4; nt++)
#pragma unroll
      for (int r = 0; r < 4; r++) {
        int c = wv * 64 + mt * 16 + quad * 4 + r;
        int q = nt * 16 + col16;
        pf[((size_t)(s * 8192 + q0 + q)) * 256 + c] = acc_o[mt][nt][r];
      }
  if (tid < 64)
    atomicAdd(&rsum[q0 + tid], rsl[0][tid] + rsl[1][tid] + rsl[2][tid] + rsl[3][tid]);
}

__global__ __launch_bounds__(256) void acomb_k(const float* pf, const float* rsum,
                                               u16* fused) {
  int tid = threadIdx.x;
  int t = blockIdx.x * 2 + (tid >> 7);
  int cp = tid & 127;
  float inv = 1.f / rsum[t];
  float v0 = 0.f, v1 = 0.f;
#pragma unroll
  for (int s = 0; s < 4; s++) {
    const float* p = pf + ((size_t)(s * 8192 + t)) * 256 + cp * 2;
    v0 += p[0]; v1 += p[1];
  }
  unsigned int pk = (unsigned)f2b(v0 * inv) | ((unsigned)f2b(v1 * inv) << 16);
  *(unsigned int*)&fused[(size_t)t * 512 + 256 + cp * 2] = pk;
}

__global__ __launch_bounds__(256) void comb_k(const float* pf, const void* bias,
                                              u16* out, int ts, int moff, int npart,
                                              int relu, const int* dflag) {
  int isbf = *dflag;
  int tid = threadIdx.x;
  int t = blockIdx.x * 64 + (tid & 63);
  int m = blockIdx.y * 8 + ((tid >> 6) << 1);
  float v0 = 0.f, v1 = 0.f;
  for (int p = 0; p < npart; p++) {
    v0 += pf[(size_t)(p * 256 + m) * 8192 + t];
    v1 += pf[(size_t)(p * 256 + m + 1) * 8192 + t];
  }
  if (bias) { v0 += rdin(bias, m, isbf); v1 += rdin(bias, m + 1, isbf); }
  if (relu) { v0 = fmaxf(v0, 0.f); v1 = fmaxf(v1, 0.f); }
  unsigned int pk = (unsigned)f2b(v0) | ((unsigned)f2b(v1) << 16);
  *(unsigned int*)&out[(size_t)t * ts + moff + m] = pk;
}

// mask + l2norm over 64 key channels; short8-vectorized; zero-inits rsum on z==0
__global__ __launch_bounds__(256) void keyfix_k(const u16* kraw3, const void* mA,
                                                const void* mB, u16* memk, u16* qk,
                                                float* rsum, const int* dflag) {
  int isbf = *dflag;
  int z = blockIdx.y;
  int n = blockIdx.x * 256 + threadIdx.x;
  int b = n >> 10, pos = n & 1023;
  if (z == 0) rsum[n] = 0.f;
  float mv = 1.f;
  if (z == 0) mv = rdin(mA, ((size_t)(b * 512 + (pos >> 5) * 16) << 9) + (pos & 31) * 16, isbf);
  else if (z == 1) mv = rdin(mB, ((size_t)(b * 512 + (pos >> 5) * 16) << 9) + (pos & 31) * 16, isbf);
  const u16* src = kraw3 + ((size_t)z * 8192 + n) * 64;
  float v[64], ss = 0.f;
#pragma unroll
  for (int c8 = 0; c8 < 8; c8++) {
    short8 xv = *(const short8*)(src + c8 * 8);
#pragma unroll
    for (int j = 0; j < 8; j++) {
      float f = b2f((u16)xv[j]) * mv;
      v[c8 * 8 + j] = f; ss += f * f;
    }
  }
  float inv = 1.f / fmaxf(sqrtf(ss), 1e-12f);
  u16* dst = (z < 2) ? memk + (size_t)(b * 2048 + z * 1024 + pos) * 64 : qk + (size_t)n * 64;
#pragma unroll
  for (int c8 = 0; c8 < 8; c8++) {
    short8 o;
#pragma unroll
    for (int j = 0; j < 8; j++) o[j] = f2b(v[c8 * 8 + j] * inv);
    *(short8*)(dst + c8 * 8) = o;
  }
}

__global__ __launch_bounds__(256) void repcls_k(const u16* decf, const void* cwgt,
                                                const void* cbias, void* out_rep,
                                                float* logits, const int* dflag) {
  int isbf = *dflag;
  int tid = threadIdx.x, lane = tid & 63, wv = tid >> 6;
  int tok = blockIdx.x * 4 + wv;
  int b = tok >> 10, pos = tok & 1023;
  const u16* src = decf + (size_t)tok * 256;
  int c0 = lane * 4;
  float v[4], ss = 0.f, a0 = 0.f, a1 = 0.f;
#pragma unroll
  for (int j = 0; j < 4; j++) {
    float x = b2f(src[c0 + j]);
    v[j] = x; ss += x * x;
    a0 = fmaf(x, rdin(cwgt, c0 + j, isbf), a0);
    a1 = fmaf(x, rdin(cwgt, 256 + c0 + j, isbf), a1);
  }
#pragma unroll
  for (int off = 32; off > 0; off >>= 1) {
    ss += __shfl_down(ss, off); a0 += __shfl_down(a0, off); a1 += __shfl_down(a1, off);
  }
  ss = __shfl(ss, 0); a0 = __shfl(a0, 0); a1 = __shfl(a1, 0);
  float inv = 1.f / fmaxf(sqrtf(ss), 1e-12f);
#pragma unroll
  for (int j = 0; j < 4; j++)
    wrout(out_rep, ((size_t)(b * 256 + c0 + j) << 10) + pos, v[j] * inv, isbf);
  if (lane == 0) {
    logits[((size_t)(b * 2) << 10) + pos]     = a0 + rdin(cbias, 0, isbf);
    logits[((size_t)(b * 2 + 1) << 10) + pos] = a1 + rdin(cbias, 1, isbf);
  }
}

__global__ __launch_bounds__(256) void resize_k(const float* logits, void* out,
                                                size_t ebase, const int* dflag) {
  int isbf = *dflag;
  int idx = blockIdx.x * 256 + threadIdx.x;
  int ox = idx & 511, oy = (idx >> 9) & 511, c = (idx >> 18) & 1, b = idx >> 19;
  float fy = (oy + 0.5f) * 0.0625f - 0.5f;
  float fx = (ox + 0.5f) * 0.0625f - 0.5f;
  int y0 = (int)floorf(fy), x0 = (int)floorf(fx);
  float wy = fy - y0, wx = fx - x0;
  int y0c = max(y0, 0), y1c = min(y0 + 1, 31);
  int x0c = max(x0, 0), x1c = min(x0 + 1, 31);
  const float* L = logits + ((size_t)(b * 2 + c) << 10);
  float v00 = L[y0c * 32 + x0c], v01 = L[y0c * 32 + x1c];
  float v10 = L[y1c * 32 + x0c], v11 = L[y1c * 32 + x1c];
  float v = (1.f - wy) * ((1.f - wx) * v00 + wx * v01) + wy * ((1.f - wx) * v10 + wx * v11);
  wrout(out, ebase + (size_t)idx, v, isbf);
}

extern "C" void kernel_launch(void* const* d_in, const int* in_sizes, int n_in,
                              void* d_out, int out_size, void* d_ws, size_t ws_size,
                              hipStream_t stream) {
  const void* query  = d_in[0];  const void* prev   = d_in[1];
  const void* prevM  = d_in[2];  const void* first  = d_in[3];
  const void* firstM = d_in[4];  const void* encQw  = d_in[5];
  const void* encQb  = d_in[6];  const void* encMw  = d_in[7];
  const void* encMb  = d_in[8];  const void* keyW   = d_in[9];
  const void* keyB   = d_in[10]; const void* valW   = d_in[11];
  const void* valB   = d_in[12]; const void* dec1W  = d_in[13];
  const void* dec1B  = d_in[14]; const void* dec2W  = d_in[15];
  const void* dec2B  = d_in[16]; const void* clsW   = d_in[17];
  const void* clsB   = d_in[18];

  u16* W = (u16*)d_ws;
  int* dflag = (int*)W;                       // 16 u16
  float* rsum   = (float*)(W + 16);           // 8192 f32 (W+16..16400)
  float* logits = (float*)(W + 16400);        // 16384 f32 (..49168)
  u16* B0 = W + 49168;
  u16* Xp    = B0;                            // encode: [2][8192][768]
  u16* feat3 = B0 + 12582912;                 // [3][8192][512]
  u16* encWb = B0 + 25165824;                 // [2][512][768] bf16 (encode phase)
  u16* wr1   = B0;                            // [256][4608] (Xp dead)
  u16* wr2   = B0 + 1179648;                  // [256][2304]
  u16* fused = B0 + 1769472;                  // [8192][512]
  u16* memv  = B0 + 5963776;                  // [8][256][2048]
  u16* memk  = B0 + 10158080;                 // [8][2048][64]
  u16* qk    = B0 + 11206656;                 // [8192][64]
  u16* kraw3 = B0 + 25165824;                 // [3][8192][64]; dead after keyfix
  u16* kvW   = B0 + 26738688;                 // [320][512] bf16; dead after keyval
  float* pf  = (float*)(B0 + 11730944);       // attn: [4][8192][256] f32; dec: [4][256][8192] f32
  u16* dbuf  = memv;
  u16* decf  = memv + 2097152;

  dim3 blk(256);
  detect_k<<<dim3(1), blk, 0, stream>>>((const u16*)encQw, dflag);

  prep1_k<<<dim3(896), blk, 0, stream>>>(first, prev, Xp, encMw, encQw, encWb, dflag);
  {
    PA a{encWb, 0, 0, 768, 0, 0, 1, 0};
    PBws b{Xp, 768, (size_t)8192 * 768};
    Epi e{0, feat3, 0, 0, (size_t)8192 * 512, 512, 0, 512,
          encMb, 0, 0, 0, 0, 0, 1.f, 1, 0};
    mgl<PBws><<<dim3(64, 4, 2), blk, 0, stream>>>(a, b, e, 12, 0, dflag);
  }
  patchify_k<<<dim3(256), blk, 0, stream>>>(query, Xp, dflag);
  {
    PA a{encWb + 393216, 0, 0, 768, 0, 0, 1, 0};
    PBws b{Xp, 768, 0};
    Epi e{0, feat3 + (size_t)2 * 8192 * 512, 0, 0, 0, 512, 0, 512,
          encQb, 0, 0, 0, 0, 0, 1.f, 1, 0};
    mgl<PBws><<<dim3(64, 4, 1), blk, 0, stream>>>(a, b, e, 12, 0, dflag);
  }

  prep2_k<<<dim3(6992), blk, 0, stream>>>(dec1W, wr1, dec2W, wr2, valW, keyW, kvW, dflag);

  {
    PA a{kvW, 0, 0, 512, 1, 0, 1, 319};
    PBws b{feat3, 512, (size_t)8192 * 512};
    Epi e{1, memv, fused, kraw3, 0, 0, 0, 320,
          valB, keyB, 0, firstM, prevM, 0, 1.f, 0, 0};
    mgl<PBws><<<dim3(64, 3, 3), blk, 0, stream>>>(a, b, e, 8, 0, dflag);
  }
  keyfix_k<<<dim3(32, 3), blk, 0, stream>>>(kraw3, firstM, prevM, memk, qk, rsum, dflag);

  attn_k<<<dim3(128, 4), blk, 0, stream>>>(qk, memk, memv, pf, rsum);
  acomb_k<<<dim3(4096), blk, 0, stream>>>(pf, rsum, fused);

  {
    PA a{wr1, 0, 0, 4608, 0, 0, 1, 0};
    PBc3 b{fused, 512, 9};
    Epi e{2, (u16*)pf, 0, 0, 0, 0, 0, 0,
          0, 0, 0, 0, 0, 0, 1.f, 0, 0};
    mg<PBc3><<<dim3(64, 2, 4), blk, 0, stream>>>(a, b, e, 18, 0, 1152, dflag);
    comb_k<<<dim3(128, 32), blk, 0, stream>>>(pf, dec1B, dbuf, 256, 0, 4, 1, dflag);
  }
  {
    PA a{wr2, 0, 0, 2304, 0, 0, 1, 0};
    PBc3 b{dbuf, 256, 8};
    Epi e{2, (u16*)pf, 0, 0, 0, 0, 0, 0,
          0, 0, 0, 0, 0, 0, 1.f, 0, 0};
    mg<PBc3><<<dim3(64, 2, 4), blk, 0, stream>>>(a, b, e, 9, 0, 576, dflag);
    comb_k<<<dim3(128, 32), blk, 0, stream>>>(pf, dec2B, decf, 256, 0, 4, 1, dflag);
  }

  repcls_k<<<dim3(2048), blk, 0, stream>>>(decf, clsW, clsB, d_out, logits, dflag);
  resize_k<<<dim3(16384), blk, 0, stream>>>(logits, d_out, (size_t)2097152, dflag);
}